// Round 1
// baseline (987.802 us; speedup 1.0000x reference)
//
#include <hip/hip_runtime.h>
#include <cstddef>
#include <math.h>

#define NTOK 1200          // B*NQ = 4*300
#define LTOT_C 17821
#define MVAL 71284         // B*LTOT

// ---------------- elementwise add ----------------
__global__ __launch_bounds__(256) void add_kernel(const float* __restrict__ a,
                                                  const float* __restrict__ b,
                                                  float* __restrict__ c, int n) {
    int i = blockIdx.x * 256 + threadIdx.x;
    if (i < n) c[i] = a[i] + b[i];
}

// ---------------- generic tiled fp32 GEMM ----------------
// C[m,n] = act( sum_k A[m,k]*W[n,k] + bias[n] (+ Res[m,n]) )
// requires: N % 64 == 0, K % 16 == 0; M may be ragged.
template<int ACT, bool RES>
__global__ __launch_bounds__(256) void gemm_kernel(
    const float* __restrict__ A, int lda,
    const float* __restrict__ W, int ldw,
    const float* __restrict__ bias,
    const float* __restrict__ Res, int ldr,
    float* __restrict__ C, int ldc,
    int M, int N, int K)
{
    __shared__ float As[16][64];
    __shared__ float Ws[16][64];
    const int bm = blockIdx.y * 64;
    const int bn = blockIdx.x * 64;
    const int t  = threadIdx.x;
    const int tx = t & 15, ty = t >> 4;
    const int r  = t >> 2;
    const int c4 = (t & 3) << 2;
    float acc[4][4] = {};
    for (int k0 = 0; k0 < K; k0 += 16) {
        float4 va = make_float4(0.f, 0.f, 0.f, 0.f);
        const int gr = bm + r;
        if (gr < M) va = *reinterpret_cast<const float4*>(A + (size_t)gr * lda + k0 + c4);
        const float4 vw = *reinterpret_cast<const float4*>(W + (size_t)(bn + r) * ldw + k0 + c4);
        __syncthreads();
        As[c4 + 0][r] = va.x; As[c4 + 1][r] = va.y; As[c4 + 2][r] = va.z; As[c4 + 3][r] = va.w;
        Ws[c4 + 0][r] = vw.x; Ws[c4 + 1][r] = vw.y; Ws[c4 + 2][r] = vw.z; Ws[c4 + 3][r] = vw.w;
        __syncthreads();
        #pragma unroll
        for (int kk = 0; kk < 16; ++kk) {
            const float4 a = *reinterpret_cast<const float4*>(&As[kk][ty << 2]);
            const float4 b = *reinterpret_cast<const float4*>(&Ws[kk][tx << 2]);
            const float av[4] = {a.x, a.y, a.z, a.w};
            const float bv[4] = {b.x, b.y, b.z, b.w};
            #pragma unroll
            for (int i = 0; i < 4; ++i) {
                #pragma unroll
                for (int j = 0; j < 4; ++j) acc[i][j] += av[i] * bv[j];
            }
        }
    }
    #pragma unroll
    for (int i = 0; i < 4; ++i) {
        const int row = bm + (ty << 2) + i;
        if (row >= M) continue;
        #pragma unroll
        for (int j = 0; j < 4; ++j) {
            const int col = bn + (tx << 2) + j;
            float v = acc[i][j] + bias[col];
            if (RES) v += Res[(size_t)row * ldr + col];
            if (ACT == 1) v = v > 0.f ? v : 0.f;
            C[(size_t)row * ldc + col] = v;
        }
    }
}

// ---------------- self-attention (per (branch,b,h), thread = one query row) ----------------
__global__ __launch_bounds__(128) void attn_kernel(
    const float* __restrict__ qkv_a, const float* __restrict__ qkv_b,
    float* __restrict__ out_a, float* __restrict__ out_b)
{
    const float scale = 0.17677669529663687f;  // 1/sqrt(32)
    const float* qkv = blockIdx.z ? qkv_b : qkv_a;
    float* outp = blockIdx.z ? out_b : out_a;
    const int b = blockIdx.y >> 3, h = blockIdx.y & 7;
    const int n = blockIdx.x * 128 + threadIdx.x;
    const bool act = n < 300;
    const float* base = qkv + (size_t)b * 300 * 768;
    float q[32];
    if (act) {
        #pragma unroll
        for (int d = 0; d < 32; ++d) q[d] = base[(size_t)n * 768 + h * 32 + d];
    }
    __shared__ float Ks[64][33];
    __shared__ float Vs[64][33];
    float mmax = -1e30f;
    for (int k0 = 0; k0 < 300; k0 += 64) {
        const int cnt = min(64, 300 - k0);
        __syncthreads();
        for (int i = threadIdx.x; i < cnt * 32; i += 128) {
            const int kr = i >> 5, d = i & 31;
            Ks[kr][d] = base[(size_t)(k0 + kr) * 768 + 256 + h * 32 + d];
        }
        __syncthreads();
        if (act) {
            for (int kk = 0; kk < cnt; ++kk) {
                float s = 0.f;
                #pragma unroll
                for (int d = 0; d < 32; ++d) s += q[d] * Ks[kk][d];
                mmax = fmaxf(mmax, s * scale);
            }
        }
    }
    float l = 0.f, o[32];
    #pragma unroll
    for (int d = 0; d < 32; ++d) o[d] = 0.f;
    for (int k0 = 0; k0 < 300; k0 += 64) {
        const int cnt = min(64, 300 - k0);
        __syncthreads();
        for (int i = threadIdx.x; i < cnt * 32; i += 128) {
            const int kr = i >> 5, d = i & 31;
            Ks[kr][d] = base[(size_t)(k0 + kr) * 768 + 256 + h * 32 + d];
            Vs[kr][d] = base[(size_t)(k0 + kr) * 768 + 512 + h * 32 + d];
        }
        __syncthreads();
        if (act) {
            for (int kk = 0; kk < cnt; ++kk) {
                float s = 0.f;
                #pragma unroll
                for (int d = 0; d < 32; ++d) s += q[d] * Ks[kk][d];
                const float e = __expf(s * scale - mmax);
                l += e;
                #pragma unroll
                for (int d = 0; d < 32; ++d) o[d] += e * Vs[kk][d];
            }
        }
    }
    if (act) {
        const float inv = 1.f / l;
        #pragma unroll
        for (int d = 0; d < 32; ++d)
            outp[((size_t)b * 300 + n) * 256 + h * 32 + d] = o[d] * inv;
    }
}

// ---------------- LayerNorm over D=256 (one block per row) ----------------
__global__ __launch_bounds__(256) void ln_kernel(
    const float* __restrict__ x, const float* __restrict__ w,
    const float* __restrict__ bvec, float* __restrict__ y)
{
    const int row = blockIdx.x, t = threadIdx.x;
    const float v = x[(size_t)row * 256 + t];
    __shared__ float r1[4], r2[4];
    float s = v;
    #pragma unroll
    for (int o = 32; o; o >>= 1) s += __shfl_xor(s, o);
    if ((t & 63) == 0) r1[t >> 6] = s;
    __syncthreads();
    const float mean = (r1[0] + r1[1] + r1[2] + r1[3]) * (1.f / 256.f);
    const float d = v - mean;
    float sq = d * d;
    #pragma unroll
    for (int o = 32; o; o >>= 1) sq += __shfl_xor(sq, o);
    if ((t & 63) == 0) r2[t >> 6] = sq;
    __syncthreads();
    const float var = (r2[0] + r2[1] + r2[2] + r2[3]) * (1.f / 256.f);
    y[(size_t)row * 256 + t] = d * rsqrtf(var + 1e-5f) * w[t] + bvec[t];
}

// ---------------- softmax over contiguous groups of 16 ----------------
__global__ __launch_bounds__(256) void softmax16_kernel(float* __restrict__ aw, int ngroups)
{
    const int g = blockIdx.x * 256 + threadIdx.x;
    if (g >= ngroups) return;
    float* p = aw + (size_t)g * 16;
    float v[16];
    float m = -1e30f;
    #pragma unroll
    for (int i = 0; i < 16; ++i) { v[i] = p[i]; m = fmaxf(m, v[i]); }
    float s = 0.f;
    #pragma unroll
    for (int i = 0; i < 16; ++i) { v[i] = __expf(v[i] - m); s += v[i]; }
    const float inv = 1.f / s;
    #pragma unroll
    for (int i = 0; i < 16; ++i) p[i] = v[i] * inv;
}

// ---------------- deformable sampling: block = (b,q), thread = (h,d) ----------------
__global__ __launch_bounds__(256) void sample_kernel(
    const float* __restrict__ value, const float* __restrict__ off,
    const float* __restrict__ aw, const float* __restrict__ ref,
    float* __restrict__ out)
{
    const int HL[4] = {100, 50, 25, 13};
    const int WL[4] = {134, 67, 34, 17};
    const int ST[4] = {0, 13400, 16750, 17600};
    const int bq = blockIdx.x;
    const int b = bq / 300;
    const int t = threadIdx.x, h = t >> 5, d = t & 31;
    const float* offp = off + (size_t)bq * 256;
    const float* awp  = aw + (size_t)bq * 128;
    const float* refp = ref + (size_t)bq * 8;
    const float* vb = value + (size_t)b * LTOT_C * 256;
    float acc = 0.f;
    #pragma unroll
    for (int l = 0; l < 4; ++l) {
        const float Wf = (float)WL[l], Hf = (float)HL[l];
        const float rx = refp[l * 2], ry = refp[l * 2 + 1];
        #pragma unroll
        for (int p = 0; p < 4; ++p) {
            const int oidx = ((h * 4 + l) * 4 + p) * 2;
            const float px = (rx + offp[oidx]     / Wf) * Wf - 0.5f;
            const float py = (ry + offp[oidx + 1] / Hf) * Hf - 0.5f;
            const float wgt = awp[h * 16 + l * 4 + p];
            const float x0f = floorf(px), y0f = floorf(py);
            const float wx = px - x0f, wy = py - y0f;
            const int x0 = (int)x0f, y0 = (int)y0f;
            float v00 = 0.f, v10 = 0.f, v01 = 0.f, v11 = 0.f;
            const bool xin0 = (x0 >= 0) & (x0 < WL[l]);
            const bool xin1 = (x0 + 1 >= 0) & (x0 + 1 < WL[l]);
            if (y0 >= 0 && y0 < HL[l]) {
                if (xin0) v00 = vb[(size_t)(ST[l] + y0 * WL[l] + x0) * 256 + h * 32 + d];
                if (xin1) v10 = vb[(size_t)(ST[l] + y0 * WL[l] + x0 + 1) * 256 + h * 32 + d];
            }
            if (y0 + 1 >= 0 && y0 + 1 < HL[l]) {
                if (xin0) v01 = vb[(size_t)(ST[l] + (y0 + 1) * WL[l] + x0) * 256 + h * 32 + d];
                if (xin1) v11 = vb[(size_t)(ST[l] + (y0 + 1) * WL[l] + x0 + 1) * 256 + h * 32 + d];
            }
            acc += wgt * (v00 * (1.f - wx) * (1.f - wy) + v10 * wx * (1.f - wy)
                        + v01 * (1.f - wx) * wy + v11 * wx * wy);
        }
    }
    out[(size_t)bq * 256 + t] = acc;
}

extern "C" void kernel_launch(void* const* d_in, const int* in_sizes, int n_in,
                              void* d_out, int out_size, void* d_ws, size_t ws_size,
                              hipStream_t stream) {
    const float* tgt[2] = {(const float*)d_in[0], (const float*)d_in[1]};
    const float* pos[2] = {(const float*)d_in[2], (const float*)d_in[3]};
    const float* ref[2] = {(const float*)d_in[4], (const float*)d_in[5]};
    const float* src[2] = {(const float*)d_in[6], (const float*)d_in[7]};
    const float* sa_in_w  = (const float*)d_in[8];
    const float* sa_in_b  = (const float*)d_in[9];
    const float* sa_out_w = (const float*)d_in[10];
    const float* sa_out_b = (const float*)d_in[11];
    const float* ln_w = (const float*)d_in[12];
    const float* ln_b = (const float*)d_in[13];
    const float* ffn_w1 = (const float*)d_in[14];
    const float* ffn_b1 = (const float*)d_in[15];
    const float* ffn_w2 = (const float*)d_in[16];
    const float* ffn_b2 = (const float*)d_in[17];
    const float* val_w = (const float*)d_in[18];
    const float* val_b = (const float*)d_in[19];
    const float* off_w = (const float*)d_in[20];
    const float* off_b = (const float*)d_in[21];
    const float* aw_w = (const float*)d_in[22];
    const float* aw_b = (const float*)d_in[23];
    const float* cout_w = (const float*)d_in[24];
    const float* cout_b = (const float*)d_in[25];

    float* ws = (float*)d_ws;
    const int STOK = NTOK * 256;  // 307200
    float* qb[2]     = {ws + 0,        ws + 307200};
    float* qkv[2]    = {ws + 614400,   ws + 1536000};
    float* attno[2]  = {ws + 2457600,  ws + 2764800};
    float* presum[2] = {ws + 3072000,  ws + 3379200};
    float* tgt2[2]   = {ws + 3686400,  ws + 3993600};
    float* offb[2]   = {ws + 4300800,  ws + 4608000};
    float* awb[2]    = {ws + 4915200,  ws + 5068800};
    float* samp[2]   = {ws + 5222400,  ws + 5529600};
    float* rbuf = ws + 5836800;
    float* tbuf = ws + 6144000;
    float* ffnh = ws + 6451200;   // NTOK*1024
    float* ffny = ws + 7680000;
    float* val[2] = {ws + 7987200, ws + 26235904};  // each MVAL*256

    float* out0 = (float*)d_out;       // tgt_RGB
    float* out1 = out0 + STOK;         // tgt_T
    float* out2 = out1 + STOK;         // F_RGB = t2_RGB
    float* out3 = out2 + STOK;         // F_T   = t2_T

    const dim3 b256(256);
    const dim3 gAdd((STOK + 255) / 256);
    const int g19 = (NTOK + 63) / 64;   // 19

    // 1. q = tgt + pos
    for (int m = 0; m < 2; ++m)
        add_kernel<<<gAdd, b256, 0, stream>>>(tgt[m], pos[m], qb[m], STOK);

    // 2. in-proj: q,k from q_m ; v from tgt_m
    for (int m = 0; m < 2; ++m) {
        gemm_kernel<0, false><<<dim3(512 / 64, g19), b256, 0, stream>>>(
            qb[m], 256, sa_in_w + (size_t)m * 768 * 256, 256, sa_in_b + m * 768,
            nullptr, 0, qkv[m], 768, NTOK, 512, 256);
        gemm_kernel<0, false><<<dim3(256 / 64, g19), b256, 0, stream>>>(
            tgt[m], 256, sa_in_w + (size_t)m * 768 * 256 + 512 * 256, 256, sa_in_b + m * 768 + 512,
            nullptr, 0, qkv[m] + 512, 768, NTOK, 256, 256);
    }

    // 3. attention
    attn_kernel<<<dim3(3, 32, 2), dim3(128), 0, stream>>>(qkv[0], qkv[1], attno[0], attno[1]);

    // 4. out-proj + residual ; 5. LN (norm2) -> tgt2
    for (int m = 0; m < 2; ++m) {
        gemm_kernel<0, true><<<dim3(4, g19), b256, 0, stream>>>(
            attno[m], 256, sa_out_w + (size_t)m * 65536, 256, sa_out_b + m * 256,
            tgt[m], 256, presum[m], 256, NTOK, 256, 256);
        ln_kernel<<<NTOK, b256, 0, stream>>>(presum[m], ln_w + (m * 3 + 1) * 256,
                                             ln_b + (m * 3 + 1) * 256, tgt2[m]);
    }

    // 6. qc = tgt2 + pos (reuse qb)
    for (int m = 0; m < 2; ++m)
        add_kernel<<<gAdd, b256, 0, stream>>>(tgt2[m], pos[m], qb[m], STOK);

    // 7. value projections (the big GEMMs).  val[0] <- src_T (RGB queries sample T memory)
    gemm_kernel<0, false><<<dim3(4, (MVAL + 63) / 64), b256, 0, stream>>>(
        src[1], 256, val_w, 256, val_b, nullptr, 0, val[0], 256, MVAL, 256, 256);
    gemm_kernel<0, false><<<dim3(4, (MVAL + 63) / 64), b256, 0, stream>>>(
        src[0], 256, val_w + 65536, 256, val_b + 256, nullptr, 0, val[1], 256, MVAL, 256, 256);

    // 8-11. offsets, attention weights, sampling, output proj per branch
    for (int m = 0; m < 2; ++m) {
        gemm_kernel<0, false><<<dim3(4, g19), b256, 0, stream>>>(
            qb[m], 256, off_w + (size_t)m * 65536, 256, off_b + m * 256,
            nullptr, 0, offb[m], 256, NTOK, 256, 256);
        gemm_kernel<0, false><<<dim3(2, g19), b256, 0, stream>>>(
            qb[m], 256, aw_w + (size_t)m * 32768, 256, aw_b + m * 128,
            nullptr, 0, awb[m], 128, NTOK, 128, 256);
        softmax16_kernel<<<dim3((NTOK * 8 + 255) / 256), b256, 0, stream>>>(awb[m], NTOK * 8);
        sample_kernel<<<dim3(NTOK), b256, 0, stream>>>(val[m], offb[m], awb[m], ref[m], samp[m]);
        gemm_kernel<0, false><<<dim3(4, g19), b256, 0, stream>>>(
            samp[m], 256, cout_w + (size_t)m * 65536, 256, cout_b + m * 256,
            nullptr, 0, (m ? out3 : out2), 256, NTOK, 256, 256);
    }

    // 12. cross residuals: r = tgt2_T + t2_RGB ; t = r + t2_T
    add_kernel<<<gAdd, b256, 0, stream>>>(tgt2[1], out2, rbuf, STOK);
    add_kernel<<<gAdd, b256, 0, stream>>>(rbuf, out3, tbuf, STOK);

    // 13. norm1 LNs -> reuse presum buffers
    ln_kernel<<<NTOK, b256, 0, stream>>>(rbuf, ln_w + 0 * 256, ln_b + 0 * 256, presum[0]);
    ln_kernel<<<NTOK, b256, 0, stream>>>(tbuf, ln_w + (3 + 0) * 256, ln_b + (3 + 0) * 256, presum[1]);

    // 14. FFN + norm3 per branch
    for (int m = 0; m < 2; ++m) {
        gemm_kernel<1, false><<<dim3(1024 / 64, g19), b256, 0, stream>>>(
            presum[m], 256, ffn_w1 + (size_t)m * 262144, 256, ffn_b1 + m * 1024,
            nullptr, 0, ffnh, 1024, NTOK, 1024, 256);
        gemm_kernel<0, true><<<dim3(4, g19), b256, 0, stream>>>(
            ffnh, 1024, ffn_w2 + (size_t)m * 262144, 1024, ffn_b2 + m * 256,
            presum[m], 256, ffny, 256, NTOK, 256, 1024);
        ln_kernel<<<NTOK, b256, 0, stream>>>(ffny, ln_w + (m * 3 + 2) * 256,
                                             ln_b + (m * 3 + 2) * 256, (m ? out1 : out0));
    }
}

// Round 2
// 657.551 us; speedup vs baseline: 1.5022x; 1.5022x over previous
//
#include <hip/hip_runtime.h>
#include <hip/hip_bf16.h>
#include <cstddef>
#include <math.h>

#define NTOK 1200          // B*NQ = 4*300
#define LTOT_C 17821
#define MVAL 71284         // B*LTOT

typedef __attribute__((ext_vector_type(8))) short bhalf8;
typedef __attribute__((ext_vector_type(4))) float f32x4;

static __device__ __forceinline__ short f2bf(float f) {
    unsigned u = __builtin_bit_cast(unsigned, f);
    u += 0x7fffu + ((u >> 16) & 1u);   // RNE
    return (short)(u >> 16);
}

// ---------------- elementwise add ----------------
__global__ __launch_bounds__(256) void add_kernel(const float* __restrict__ a,
                                                  const float* __restrict__ b,
                                                  float* __restrict__ c, int n) {
    int i = blockIdx.x * 256 + threadIdx.x;
    if (i < n) c[i] = a[i] + b[i];
}

// ---------------- generic tiled fp32 GEMM (small projections) ----------------
template<int ACT, bool RES>
__global__ __launch_bounds__(256) void gemm_kernel(
    const float* __restrict__ A, int lda,
    const float* __restrict__ W, int ldw,
    const float* __restrict__ bias,
    const float* __restrict__ Res, int ldr,
    float* __restrict__ C, int ldc,
    int M, int N, int K)
{
    __shared__ float As[16][64];
    __shared__ float Ws[16][64];
    const int bm = blockIdx.y * 64;
    const int bn = blockIdx.x * 64;
    const int t  = threadIdx.x;
    const int tx = t & 15, ty = t >> 4;
    const int r  = t >> 2;
    const int c4 = (t & 3) << 2;
    float acc[4][4] = {};
    for (int k0 = 0; k0 < K; k0 += 16) {
        float4 va = make_float4(0.f, 0.f, 0.f, 0.f);
        const int gr = bm + r;
        if (gr < M) va = *reinterpret_cast<const float4*>(A + (size_t)gr * lda + k0 + c4);
        const float4 vw = *reinterpret_cast<const float4*>(W + (size_t)(bn + r) * ldw + k0 + c4);
        __syncthreads();
        As[c4 + 0][r] = va.x; As[c4 + 1][r] = va.y; As[c4 + 2][r] = va.z; As[c4 + 3][r] = va.w;
        Ws[c4 + 0][r] = vw.x; Ws[c4 + 1][r] = vw.y; Ws[c4 + 2][r] = vw.z; Ws[c4 + 3][r] = vw.w;
        __syncthreads();
        #pragma unroll
        for (int kk = 0; kk < 16; ++kk) {
            const float4 a = *reinterpret_cast<const float4*>(&As[kk][ty << 2]);
            const float4 b = *reinterpret_cast<const float4*>(&Ws[kk][tx << 2]);
            const float av[4] = {a.x, a.y, a.z, a.w};
            const float bv[4] = {b.x, b.y, b.z, b.w};
            #pragma unroll
            for (int i = 0; i < 4; ++i) {
                #pragma unroll
                for (int j = 0; j < 4; ++j) acc[i][j] += av[i] * bv[j];
            }
        }
    }
    #pragma unroll
    for (int i = 0; i < 4; ++i) {
        const int row = bm + (ty << 2) + i;
        if (row >= M) continue;
        #pragma unroll
        for (int j = 0; j < 4; ++j) {
            const int col = bn + (tx << 2) + j;
            float v = acc[i][j] + bias[col];
            if (RES) v += Res[(size_t)row * ldr + col];
            if (ACT == 1) v = v > 0.f ? v : 0.f;
            C[(size_t)row * ldc + col] = v;
        }
    }
}

// ---------------- bf16 MFMA GEMM for value projection ----------------
// C[M,256] = A[M,256](fp32->bf16) @ W[256,256]^T (fp32->bf16) + bias
// block: 256 thr = 4 waves; tile 128(M) x 256(N), BK=64; wave w owns cols [w*64, w*64+64)
__global__ __launch_bounds__(256) void gemm_mfma_val(
    const float* __restrict__ A,
    const float* __restrict__ W,
    const float* __restrict__ bias,
    float* __restrict__ C, int M)
{
    __shared__ short As[128 * 64];   // [m][k] bf16, k in 8-elem groups, group ^= (m&7)
    __shared__ short Bs[256 * 64];   // [n][k] bf16, group ^= (n&7)
    const int t = threadIdx.x;
    const int wave = t >> 6, lane = t & 63;
    const int l15 = lane & 15, l4 = lane >> 4;   // 0..3
    const int bm = blockIdx.x * 128;
    f32x4 acc[8][4] = {};

    for (int k0 = 0; k0 < 256; k0 += 64) {
        __syncthreads();
        // stage A: 1024 groups of 8 elems
        #pragma unroll
        for (int i = 0; i < 4; ++i) {
            const int G = t + i * 256;
            const int m = G >> 3, g = G & 7;
            const int row = bm + m;
            float4 f0 = make_float4(0.f, 0.f, 0.f, 0.f), f1 = f0;
            if (row < M) {
                const float* s = A + (size_t)row * 256 + k0 + g * 8;
                f0 = *reinterpret_cast<const float4*>(s);
                f1 = *reinterpret_cast<const float4*>(s + 4);
            }
            bhalf8 h;
            h[0] = f2bf(f0.x); h[1] = f2bf(f0.y); h[2] = f2bf(f0.z); h[3] = f2bf(f0.w);
            h[4] = f2bf(f1.x); h[5] = f2bf(f1.y); h[6] = f2bf(f1.z); h[7] = f2bf(f1.w);
            *reinterpret_cast<bhalf8*>(&As[m * 64 + ((g ^ (m & 7)) << 3)]) = h;
        }
        // stage B (weights): 2048 groups of 8 elems
        #pragma unroll
        for (int i = 0; i < 8; ++i) {
            const int G = t + i * 256;
            const int n = G >> 3, g = G & 7;
            const float* s = W + (size_t)n * 256 + k0 + g * 8;
            const float4 f0 = *reinterpret_cast<const float4*>(s);
            const float4 f1 = *reinterpret_cast<const float4*>(s + 4);
            bhalf8 h;
            h[0] = f2bf(f0.x); h[1] = f2bf(f0.y); h[2] = f2bf(f0.z); h[3] = f2bf(f0.w);
            h[4] = f2bf(f1.x); h[5] = f2bf(f1.y); h[6] = f2bf(f1.z); h[7] = f2bf(f1.w);
            *reinterpret_cast<bhalf8*>(&Bs[n * 64 + ((g ^ (n & 7)) << 3)]) = h;
        }
        __syncthreads();
        #pragma unroll
        for (int kf = 0; kf < 2; ++kf) {
            bhalf8 af[8], bfv[4];
            #pragma unroll
            for (int mf = 0; mf < 8; ++mf) {
                const int m = (mf << 4) + l15;
                const int g = ((kf << 2) + l4) ^ (m & 7);
                af[mf] = *reinterpret_cast<const bhalf8*>(&As[m * 64 + (g << 3)]);
            }
            #pragma unroll
            for (int nf = 0; nf < 4; ++nf) {
                const int n = (wave << 6) + (nf << 4) + l15;
                const int g = ((kf << 2) + l4) ^ (n & 7);
                bfv[nf] = *reinterpret_cast<const bhalf8*>(&Bs[n * 64 + (g << 3)]);
            }
            #pragma unroll
            for (int mf = 0; mf < 8; ++mf)
                #pragma unroll
                for (int nf = 0; nf < 4; ++nf)
                    acc[mf][nf] = __builtin_amdgcn_mfma_f32_16x16x32_bf16(
                        af[mf], bfv[nf], acc[mf][nf], 0, 0, 0);
        }
    }
    // epilogue: row = bm + mf*16 + l4*4 + j ; col = wave*64 + nf*16 + l15
    float biasr[4];
    #pragma unroll
    for (int nf = 0; nf < 4; ++nf) biasr[nf] = bias[(wave << 6) + (nf << 4) + l15];
    #pragma unroll
    for (int mf = 0; mf < 8; ++mf) {
        #pragma unroll
        for (int j = 0; j < 4; ++j) {
            const int r = bm + (mf << 4) + (l4 << 2) + j;
            if (r >= M) continue;
            float* crow = C + (size_t)r * 256 + (wave << 6);
            #pragma unroll
            for (int nf = 0; nf < 4; ++nf)
                crow[(nf << 4) + l15] = acc[mf][nf][j] + biasr[nf];
        }
    }
}

// ---------------- self-attention v2: key-parallel online softmax ----------------
// grid (qtile=10, b*8+h=32, branch=2), block 256 = (32 queries) x (8 key groups)
__global__ __launch_bounds__(256) void attn2_kernel(
    const float* __restrict__ qkv_a, const float* __restrict__ qkv_b,
    float* __restrict__ out_a, float* __restrict__ out_b)
{
    const float scale = 0.17677669529663687f;  // 1/sqrt(32)
    const float* qkv = blockIdx.z ? qkv_b : qkv_a;
    float* outp = blockIdx.z ? out_b : out_a;
    const int b = blockIdx.y >> 3, h = blockIdx.y & 7;
    const int t = threadIdx.x;
    const int ql = t & 31;
    const int kg = t >> 5;
    const int q = blockIdx.x * 32 + ql;
    const bool act = q < 300;
    const float* base = qkv + (size_t)b * 300 * 768;

    float qreg[32];
    if (act) {
        const float4* qp = reinterpret_cast<const float4*>(base + (size_t)q * 768 + h * 32);
        #pragma unroll
        for (int d4 = 0; d4 < 8; ++d4) {
            const float4 v = qp[d4];
            qreg[d4 * 4 + 0] = v.x; qreg[d4 * 4 + 1] = v.y;
            qreg[d4 * 4 + 2] = v.z; qreg[d4 * 4 + 3] = v.w;
        }
    }
    __shared__ float Ks[64][32];
    __shared__ float Vs[64][32];
    float m = -1e30f, l = 0.f, o[32];
    #pragma unroll
    for (int d = 0; d < 32; ++d) o[d] = 0.f;

    for (int k0 = 0; k0 < 300; k0 += 64) {
        const int cnt = min(64, 300 - k0);
        __syncthreads();
        for (int i = t; i < cnt * 32; i += 256) {
            const int kr = i >> 5, d = i & 31;
            Ks[kr][d] = base[(size_t)(k0 + kr) * 768 + 256 + h * 32 + d];
            Vs[kr][d] = base[(size_t)(k0 + kr) * 768 + 512 + h * 32 + d];
        }
        __syncthreads();
        if (act) {
            for (int kk = kg; kk < cnt; kk += 8) {
                const float4* krow = reinterpret_cast<const float4*>(&Ks[kk][0]);
                float s = 0.f;
                #pragma unroll
                for (int d4 = 0; d4 < 8; ++d4) {
                    const float4 kv = krow[d4];
                    s += qreg[d4 * 4 + 0] * kv.x + qreg[d4 * 4 + 1] * kv.y
                       + qreg[d4 * 4 + 2] * kv.z + qreg[d4 * 4 + 3] * kv.w;
                }
                s *= scale;
                const float4* vrow = reinterpret_cast<const float4*>(&Vs[kk][0]);
                if (s <= m) {
                    const float e = __expf(s - m);
                    l += e;
                    #pragma unroll
                    for (int d4 = 0; d4 < 8; ++d4) {
                        const float4 vv = vrow[d4];
                        o[d4 * 4 + 0] += e * vv.x; o[d4 * 4 + 1] += e * vv.y;
                        o[d4 * 4 + 2] += e * vv.z; o[d4 * 4 + 3] += e * vv.w;
                    }
                } else {
                    const float c = __expf(m - s);
                    l = l * c + 1.f;
                    #pragma unroll
                    for (int d4 = 0; d4 < 8; ++d4) {
                        const float4 vv = vrow[d4];
                        o[d4 * 4 + 0] = o[d4 * 4 + 0] * c + vv.x;
                        o[d4 * 4 + 1] = o[d4 * 4 + 1] * c + vv.y;
                        o[d4 * 4 + 2] = o[d4 * 4 + 2] * c + vv.z;
                        o[d4 * 4 + 3] = o[d4 * 4 + 3] * c + vv.w;
                    }
                    m = s;
                }
            }
        }
    }
    // merge the 8 partials per query
    __shared__ float pm[32][8];
    __shared__ float pl[32][8];
    __shared__ float po[8][32][33];   // [kg][d][ql]
    pm[ql][kg] = m; pl[ql][kg] = l;
    #pragma unroll
    for (int d = 0; d < 32; ++d) po[kg][d][ql] = o[d];
    __syncthreads();
    if (kg == 0) {
        float M = pm[ql][0];
        #pragma unroll
        for (int i = 1; i < 8; ++i) M = fmaxf(M, pm[ql][i]);
        float L = 0.f;
        #pragma unroll
        for (int i = 0; i < 8; ++i) L += pl[ql][i] * __expf(pm[ql][i] - M);
        const float invL = 1.f / L;
        #pragma unroll
        for (int i = 0; i < 8; ++i) pm[ql][i] = __expf(pm[ql][i] - M) * invL;
    }
    __syncthreads();
    if (act) {
        #pragma unroll
        for (int dd = 0; dd < 4; ++dd) {
            const int d = kg * 4 + dd;
            float v = 0.f;
            #pragma unroll
            for (int i = 0; i < 8; ++i) v += pm[ql][i] * po[i][d][ql];
            outp[((size_t)b * 300 + q) * 256 + h * 32 + d] = v;
        }
    }
}

// ---------------- LayerNorm over D=256 (one block per row) ----------------
__global__ __launch_bounds__(256) void ln_kernel(
    const float* __restrict__ x, const float* __restrict__ w,
    const float* __restrict__ bvec, float* __restrict__ y)
{
    const int row = blockIdx.x, t = threadIdx.x;
    const float v = x[(size_t)row * 256 + t];
    __shared__ float r1[4], r2[4];
    float s = v;
    #pragma unroll
    for (int o = 32; o; o >>= 1) s += __shfl_xor(s, o);
    if ((t & 63) == 0) r1[t >> 6] = s;
    __syncthreads();
    const float mean = (r1[0] + r1[1] + r1[2] + r1[3]) * (1.f / 256.f);
    const float d = v - mean;
    float sq = d * d;
    #pragma unroll
    for (int o = 32; o; o >>= 1) sq += __shfl_xor(sq, o);
    if ((t & 63) == 0) r2[t >> 6] = sq;
    __syncthreads();
    const float var = (r2[0] + r2[1] + r2[2] + r2[3]) * (1.f / 256.f);
    y[(size_t)row * 256 + t] = d * rsqrtf(var + 1e-5f) * w[t] + bvec[t];
}

// ---------------- softmax over contiguous groups of 16 ----------------
__global__ __launch_bounds__(256) void softmax16_kernel(float* __restrict__ aw, int ngroups)
{
    const int g = blockIdx.x * 256 + threadIdx.x;
    if (g >= ngroups) return;
    float* p = aw + (size_t)g * 16;
    float v[16];
    float m = -1e30f;
    #pragma unroll
    for (int i = 0; i < 16; ++i) { v[i] = p[i]; m = fmaxf(m, v[i]); }
    float s = 0.f;
    #pragma unroll
    for (int i = 0; i < 16; ++i) { v[i] = __expf(v[i] - m); s += v[i]; }
    const float inv = 1.f / s;
    #pragma unroll
    for (int i = 0; i < 16; ++i) p[i] = v[i] * inv;
}

// ---------------- deformable sampling: block = (b,q), thread = (h,d) ----------------
__global__ __launch_bounds__(256) void sample_kernel(
    const float* __restrict__ value, const float* __restrict__ off,
    const float* __restrict__ aw, const float* __restrict__ ref,
    float* __restrict__ out)
{
    const int HL[4] = {100, 50, 25, 13};
    const int WL[4] = {134, 67, 34, 17};
    const int ST[4] = {0, 13400, 16750, 17600};
    const int bq = blockIdx.x;
    const int b = bq / 300;
    const int t = threadIdx.x, h = t >> 5, d = t & 31;
    const float* offp = off + (size_t)bq * 256;
    const float* awp  = aw + (size_t)bq * 128;
    const float* refp = ref + (size_t)bq * 8;
    const float* vb = value + (size_t)b * LTOT_C * 256;
    float acc = 0.f;
    #pragma unroll
    for (int l = 0; l < 4; ++l) {
        const float Wf = (float)WL[l], Hf = (float)HL[l];
        const float rx = refp[l * 2], ry = refp[l * 2 + 1];
        #pragma unroll
        for (int p = 0; p < 4; ++p) {
            const int oidx = ((h * 4 + l) * 4 + p) * 2;
            const float px = (rx + offp[oidx]     / Wf) * Wf - 0.5f;
            const float py = (ry + offp[oidx + 1] / Hf) * Hf - 0.5f;
            const float wgt = awp[h * 16 + l * 4 + p];
            const float x0f = floorf(px), y0f = floorf(py);
            const float wx = px - x0f, wy = py - y0f;
            const int x0 = (int)x0f, y0 = (int)y0f;
            float v00 = 0.f, v10 = 0.f, v01 = 0.f, v11 = 0.f;
            const bool xin0 = (x0 >= 0) & (x0 < WL[l]);
            const bool xin1 = (x0 + 1 >= 0) & (x0 + 1 < WL[l]);
            if (y0 >= 0 && y0 < HL[l]) {
                if (xin0) v00 = vb[(size_t)(ST[l] + y0 * WL[l] + x0) * 256 + h * 32 + d];
                if (xin1) v10 = vb[(size_t)(ST[l] + y0 * WL[l] + x0 + 1) * 256 + h * 32 + d];
            }
            if (y0 + 1 >= 0 && y0 + 1 < HL[l]) {
                if (xin0) v01 = vb[(size_t)(ST[l] + (y0 + 1) * WL[l] + x0) * 256 + h * 32 + d];
                if (xin1) v11 = vb[(size_t)(ST[l] + (y0 + 1) * WL[l] + x0 + 1) * 256 + h * 32 + d];
            }
            acc += wgt * (v00 * (1.f - wx) * (1.f - wy) + v10 * wx * (1.f - wy)
                        + v01 * (1.f - wx) * wy + v11 * wx * wy);
        }
    }
    out[(size_t)bq * 256 + t] = acc;
}

extern "C" void kernel_launch(void* const* d_in, const int* in_sizes, int n_in,
                              void* d_out, int out_size, void* d_ws, size_t ws_size,
                              hipStream_t stream) {
    const float* tgt[2] = {(const float*)d_in[0], (const float*)d_in[1]};
    const float* pos[2] = {(const float*)d_in[2], (const float*)d_in[3]};
    const float* ref[2] = {(const float*)d_in[4], (const float*)d_in[5]};
    const float* src[2] = {(const float*)d_in[6], (const float*)d_in[7]};
    const float* sa_in_w  = (const float*)d_in[8];
    const float* sa_in_b  = (const float*)d_in[9];
    const float* sa_out_w = (const float*)d_in[10];
    const float* sa_out_b = (const float*)d_in[11];
    const float* ln_w = (const float*)d_in[12];
    const float* ln_b = (const float*)d_in[13];
    const float* ffn_w1 = (const float*)d_in[14];
    const float* ffn_b1 = (const float*)d_in[15];
    const float* ffn_w2 = (const float*)d_in[16];
    const float* ffn_b2 = (const float*)d_in[17];
    const float* val_w = (const float*)d_in[18];
    const float* val_b = (const float*)d_in[19];
    const float* off_w = (const float*)d_in[20];
    const float* off_b = (const float*)d_in[21];
    const float* aw_w = (const float*)d_in[22];
    const float* aw_b = (const float*)d_in[23];
    const float* cout_w = (const float*)d_in[24];
    const float* cout_b = (const float*)d_in[25];

    float* ws = (float*)d_ws;
    const int STOK = NTOK * 256;  // 307200
    float* qb[2]     = {ws + 0,        ws + 307200};
    float* qkv[2]    = {ws + 614400,   ws + 1536000};
    float* attno[2]  = {ws + 2457600,  ws + 2764800};
    float* presum[2] = {ws + 3072000,  ws + 3379200};
    float* tgt2[2]   = {ws + 3686400,  ws + 3993600};
    float* offb[2]   = {ws + 4300800,  ws + 4608000};
    float* awb[2]    = {ws + 4915200,  ws + 5068800};
    float* samp[2]   = {ws + 5222400,  ws + 5529600};
    float* rbuf = ws + 5836800;
    float* tbuf = ws + 6144000;
    float* ffnh = ws + 6451200;   // NTOK*1024
    float* ffny = ws + 7680000;
    float* val[2] = {ws + 7987200, ws + 26235904};  // each MVAL*256

    float* out0 = (float*)d_out;       // tgt_RGB
    float* out1 = out0 + STOK;         // tgt_T
    float* out2 = out1 + STOK;         // F_RGB = t2_RGB
    float* out3 = out2 + STOK;         // F_T   = t2_T

    const dim3 b256(256);
    const dim3 gAdd((STOK + 255) / 256);
    const int g19 = (NTOK + 63) / 64;   // 19

    // 1. q = tgt + pos
    for (int m = 0; m < 2; ++m)
        add_kernel<<<gAdd, b256, 0, stream>>>(tgt[m], pos[m], qb[m], STOK);

    // 2. in-proj: q,k from q_m ; v from tgt_m
    for (int m = 0; m < 2; ++m) {
        gemm_kernel<0, false><<<dim3(512 / 64, g19), b256, 0, stream>>>(
            qb[m], 256, sa_in_w + (size_t)m * 768 * 256, 256, sa_in_b + m * 768,
            nullptr, 0, qkv[m], 768, NTOK, 512, 256);
        gemm_kernel<0, false><<<dim3(256 / 64, g19), b256, 0, stream>>>(
            tgt[m], 256, sa_in_w + (size_t)m * 768 * 256 + 512 * 256, 256, sa_in_b + m * 768 + 512,
            nullptr, 0, qkv[m] + 512, 768, NTOK, 256, 256);
    }

    // 3. attention (key-parallel online softmax)
    attn2_kernel<<<dim3(10, 32, 2), b256, 0, stream>>>(qkv[0], qkv[1], attno[0], attno[1]);

    // 4. out-proj + residual ; 5. LN (norm2) -> tgt2
    for (int m = 0; m < 2; ++m) {
        gemm_kernel<0, true><<<dim3(4, g19), b256, 0, stream>>>(
            attno[m], 256, sa_out_w + (size_t)m * 65536, 256, sa_out_b + m * 256,
            tgt[m], 256, presum[m], 256, NTOK, 256, 256);
        ln_kernel<<<NTOK, b256, 0, stream>>>(presum[m], ln_w + (m * 3 + 1) * 256,
                                             ln_b + (m * 3 + 1) * 256, tgt2[m]);
    }

    // 6. qc = tgt2 + pos (reuse qb)
    for (int m = 0; m < 2; ++m)
        add_kernel<<<gAdd, b256, 0, stream>>>(tgt2[m], pos[m], qb[m], STOK);

    // 7. value projections: bf16 MFMA.  val[0] <- src_T, val[1] <- src_RGB
    {
        const int gM = (MVAL + 127) / 128;  // 557
        gemm_mfma_val<<<dim3(gM), b256, 0, stream>>>(src[1], val_w, val_b, val[0], MVAL);
        gemm_mfma_val<<<dim3(gM), b256, 0, stream>>>(src[0], val_w + 65536, val_b + 256, val[1], MVAL);
    }

    // 8-11. offsets, attention weights, sampling, output proj per branch
    for (int m = 0; m < 2; ++m) {
        gemm_kernel<0, false><<<dim3(4, g19), b256, 0, stream>>>(
            qb[m], 256, off_w + (size_t)m * 65536, 256, off_b + m * 256,
            nullptr, 0, offb[m], 256, NTOK, 256, 256);
        gemm_kernel<0, false><<<dim3(2, g19), b256, 0, stream>>>(
            qb[m], 256, aw_w + (size_t)m * 32768, 256, aw_b + m * 128,
            nullptr, 0, awb[m], 128, NTOK, 128, 256);
        softmax16_kernel<<<dim3((NTOK * 8 + 255) / 256), b256, 0, stream>>>(awb[m], NTOK * 8);
        sample_kernel<<<dim3(NTOK), b256, 0, stream>>>(val[m], offb[m], awb[m], ref[m], samp[m]);
        gemm_kernel<0, false><<<dim3(4, g19), b256, 0, stream>>>(
            samp[m], 256, cout_w + (size_t)m * 65536, 256, cout_b + m * 256,
            nullptr, 0, (m ? out3 : out2), 256, NTOK, 256, 256);
    }

    // 12. cross residuals: r = tgt2_T + t2_RGB ; t = r + t2_T
    add_kernel<<<gAdd, b256, 0, stream>>>(tgt2[1], out2, rbuf, STOK);
    add_kernel<<<gAdd, b256, 0, stream>>>(rbuf, out3, tbuf, STOK);

    // 13. norm1 LNs
    ln_kernel<<<NTOK, b256, 0, stream>>>(rbuf, ln_w + 0 * 256, ln_b + 0 * 256, presum[0]);
    ln_kernel<<<NTOK, b256, 0, stream>>>(tbuf, ln_w + (3 + 0) * 256, ln_b + (3 + 0) * 256, presum[1]);

    // 14. FFN + norm3 per branch
    for (int m = 0; m < 2; ++m) {
        gemm_kernel<1, false><<<dim3(1024 / 64, g19), b256, 0, stream>>>(
            presum[m], 256, ffn_w1 + (size_t)m * 262144, 256, ffn_b1 + m * 1024,
            nullptr, 0, ffnh, 1024, NTOK, 1024, 256);
        gemm_kernel<0, true><<<dim3(4, g19), b256, 0, stream>>>(
            ffnh, 1024, ffn_w2 + (size_t)m * 262144, 1024, ffn_b2 + m * 256,
            presum[m], 256, ffny, 256, NTOK, 256, 1024);
        ln_kernel<<<NTOK, b256, 0, stream>>>(ffny, ln_w + (m * 3 + 2) * 256,
                                             ln_b + (m * 3 + 2) * 256, (m ? out1 : out0));
    }
}

// Round 3
// 358.950 us; speedup vs baseline: 2.7519x; 1.8319x over previous
//
#include <hip/hip_runtime.h>
#include <cstddef>
#include <math.h>

#define NTOK 1200          // B*NQ = 4*300
#define LTOT_C 17821
#define MVAL 71284         // B*LTOT
#define STOK (NTOK * 256)  // 307200

typedef __attribute__((ext_vector_type(8))) short bhalf8;
typedef __attribute__((ext_vector_type(4))) float f32x4;

static __device__ __forceinline__ short f2bf(float f) {
    unsigned u = __builtin_bit_cast(unsigned, f);
    u += 0x7fffu + ((u >> 16) & 1u);   // RNE
    return (short)(u >> 16);
}
static __device__ __forceinline__ float bf2f(short s) {
    unsigned u = ((unsigned)(unsigned short)s) << 16;
    return __builtin_bit_cast(float, u);
}
static __device__ __forceinline__ bhalf8 cvt8(float4 a, float4 b) {
    bhalf8 h;
    h[0] = f2bf(a.x); h[1] = f2bf(a.y); h[2] = f2bf(a.z); h[3] = f2bf(a.w);
    h[4] = f2bf(b.x); h[5] = f2bf(b.y); h[6] = f2bf(b.z); h[7] = f2bf(b.w);
    return h;
}

// ---------------- weight convert fp32 -> bf16 ----------------
struct WcvtArgs { const float* s[8]; short* d[8]; int n[8]; };
__global__ __launch_bounds__(256) void wcvt(WcvtArgs a) {
    const int ti = blockIdx.y;
    const float* s = a.s[ti];
    short* d = a.d[ti];
    const int n = a.n[ti];
    for (int base = (blockIdx.x * 256 + threadIdx.x) * 8; base < n; base += gridDim.x * 256 * 8) {
        const float4 f0 = *reinterpret_cast<const float4*>(s + base);
        const float4 f1 = *reinterpret_cast<const float4*>(s + base + 4);
        *reinterpret_cast<bhalf8*>(d + base) = cvt8(f0, f1);
    }
}

// ---------------- activation prep: qb=bf16(tgt+pos), tgtb=bf16(tgt) ----------------
__global__ __launch_bounds__(256) void prep_act(
    const float* __restrict__ tgt0, const float* __restrict__ tgt1,
    const float* __restrict__ pos0, const float* __restrict__ pos1,
    short* __restrict__ qb_bf, short* __restrict__ tgtb)
{
    const int z = blockIdx.y;
    const float* tg = z ? tgt1 : tgt0;
    const float* ps = z ? pos1 : pos0;
    const int base = (blockIdx.x * 256 + threadIdx.x) * 8;
    if (base >= STOK) return;
    const float4 t0 = *reinterpret_cast<const float4*>(tg + base);
    const float4 t1 = *reinterpret_cast<const float4*>(tg + base + 4);
    const float4 p0 = *reinterpret_cast<const float4*>(ps + base);
    const float4 p1 = *reinterpret_cast<const float4*>(ps + base + 4);
    float4 s0 = make_float4(t0.x + p0.x, t0.y + p0.y, t0.z + p0.z, t0.w + p0.w);
    float4 s1 = make_float4(t1.x + p1.x, t1.y + p1.y, t1.z + p1.z, t1.w + p1.w);
    *reinterpret_cast<bhalf8*>(qb_bf + (size_t)z * STOK + base) = cvt8(s0, s1);
    *reinterpret_cast<bhalf8*>(tgtb + (size_t)z * STOK + base) = cvt8(t0, t1);
}

// ---------------- unified bf16 MFMA GEMM ----------------
// C = act( A[M,K] @ W[N,K]^T + bias (+Res) );  tile 128x128, 4 waves (2x2), BK=64
// A: bf16 (or fp32 with in-flight convert).  N = gridDim.x*128 (multiple of 128).
template<bool A_FP32, bool HASRES, bool RELU, bool OUT_BF16>
__global__ __launch_bounds__(256) void gemm_bf16(
    const void* __restrict__ Av, size_t aStrideZ, int lda,
    const short* __restrict__ Wv, size_t wStrideZ, int ldw,
    const float* __restrict__ bias, size_t biasStrideZ,
    const float* __restrict__ Res0, const float* __restrict__ Res1, int ldr,
    void* __restrict__ Cv, size_t cStrideZ, int ldc,
    int M, int K)
{
    __shared__ short As[128 * 64];
    __shared__ short Bs[128 * 64];
    const int z = blockIdx.z;
    const short* W = Wv + (size_t)z * wStrideZ;
    const float* bz = bias + (size_t)z * biasStrideZ;
    const int t = threadIdx.x;
    const int wave = t >> 6, lane = t & 63;
    const int l15 = lane & 15, l4 = lane >> 4;
    const int wr = wave >> 1, wc = wave & 1;
    const int bm = blockIdx.y * 128, bn = blockIdx.x * 128;
    f32x4 acc[4][4] = {};

    for (int k0 = 0; k0 < K; k0 += 64) {
        __syncthreads();
        #pragma unroll
        for (int i = 0; i < 4; ++i) {
            const int G = t + i * 256;
            const int m = G >> 3, g = G & 7;
            const int row = bm + m;
            bhalf8 h;
            #pragma unroll
            for (int q = 0; q < 8; ++q) h[q] = 0;
            if (A_FP32) {
                if (row < M) {
                    const float* s = (const float*)Av + (size_t)z * aStrideZ + (size_t)row * lda + k0 + g * 8;
                    h = cvt8(*reinterpret_cast<const float4*>(s),
                             *reinterpret_cast<const float4*>(s + 4));
                }
            } else {
                if (row < M)
                    h = *reinterpret_cast<const bhalf8*>((const short*)Av + (size_t)z * aStrideZ + (size_t)row * lda + k0 + g * 8);
            }
            *reinterpret_cast<bhalf8*>(&As[m * 64 + ((g ^ (m & 7)) << 3)]) = h;
            const bhalf8 hb = *reinterpret_cast<const bhalf8*>(W + (size_t)(bn + m) * ldw + k0 + g * 8);
            *reinterpret_cast<bhalf8*>(&Bs[m * 64 + ((g ^ (m & 7)) << 3)]) = hb;
        }
        __syncthreads();
        #pragma unroll
        for (int kf = 0; kf < 2; ++kf) {
            bhalf8 af[4], bfv[4];
            #pragma unroll
            for (int mf = 0; mf < 4; ++mf) {
                const int m = (wr << 6) + (mf << 4) + l15;
                const int g = ((kf << 2) + l4) ^ (m & 7);
                af[mf] = *reinterpret_cast<const bhalf8*>(&As[m * 64 + (g << 3)]);
            }
            #pragma unroll
            for (int nf = 0; nf < 4; ++nf) {
                const int n = (wc << 6) + (nf << 4) + l15;
                const int g = ((kf << 2) + l4) ^ (n & 7);
                bfv[nf] = *reinterpret_cast<const bhalf8*>(&Bs[n * 64 + (g << 3)]);
            }
            #pragma unroll
            for (int mf = 0; mf < 4; ++mf)
                #pragma unroll
                for (int nf = 0; nf < 4; ++nf)
                    acc[mf][nf] = __builtin_amdgcn_mfma_f32_16x16x32_bf16(
                        af[mf], bfv[nf], acc[mf][nf], 0, 0, 0);
        }
    }
    const float* Rz = HASRES ? (z ? Res1 : Res0) : nullptr;
    float br[4];
    #pragma unroll
    for (int nf = 0; nf < 4; ++nf) br[nf] = bz[bn + (wc << 6) + (nf << 4) + l15];
    #pragma unroll
    for (int mf = 0; mf < 4; ++mf) {
        #pragma unroll
        for (int j = 0; j < 4; ++j) {
            const int row = bm + (wr << 6) + (mf << 4) + (l4 << 2) + j;
            if (row >= M) continue;
            const int colbase = bn + (wc << 6);
            #pragma unroll
            for (int nf = 0; nf < 4; ++nf) {
                const int col = colbase + (nf << 4) + l15;
                float v = acc[mf][nf][j] + br[nf];
                if (HASRES) v += Rz[(size_t)row * ldr + col];
                if (RELU) v = fmaxf(v, 0.f);
                if (OUT_BF16)
                    ((short*)Cv + (size_t)z * cStrideZ)[(size_t)row * ldc + col] = f2bf(v);
                else
                    ((float*)Cv + (size_t)z * cStrideZ)[(size_t)row * ldc + col] = v;
            }
        }
    }
}

// ---------------- self-attention: key-parallel online softmax, bf16 out ----------------
__global__ __launch_bounds__(256) void attn2_kernel(
    const float* __restrict__ qkv_base, short* __restrict__ out_base)
{
    const float scale = 0.17677669529663687f;  // 1/sqrt(32)
    const float* qkv = qkv_base + (size_t)blockIdx.z * 921600;
    short* outp = out_base + (size_t)blockIdx.z * STOK;
    const int b = blockIdx.y >> 3, h = blockIdx.y & 7;
    const int t = threadIdx.x;
    const int ql = t & 31;
    const int kg = t >> 5;
    const int q = blockIdx.x * 32 + ql;
    const bool act = q < 300;
    const float* base = qkv + (size_t)b * 300 * 768;

    float qreg[32];
    if (act) {
        const float4* qp = reinterpret_cast<const float4*>(base + (size_t)q * 768 + h * 32);
        #pragma unroll
        for (int d4 = 0; d4 < 8; ++d4) {
            const float4 v = qp[d4];
            qreg[d4 * 4 + 0] = v.x; qreg[d4 * 4 + 1] = v.y;
            qreg[d4 * 4 + 2] = v.z; qreg[d4 * 4 + 3] = v.w;
        }
    }
    __shared__ float Ks[64][32];
    __shared__ float Vs[64][32];
    float m = -1e30f, l = 0.f, o[32];
    #pragma unroll
    for (int d = 0; d < 32; ++d) o[d] = 0.f;

    for (int k0 = 0; k0 < 300; k0 += 64) {
        const int cnt = min(64, 300 - k0);
        __syncthreads();
        for (int i = t; i < cnt * 32; i += 256) {
            const int kr = i >> 5, d = i & 31;
            Ks[kr][d] = base[(size_t)(k0 + kr) * 768 + 256 + h * 32 + d];
            Vs[kr][d] = base[(size_t)(k0 + kr) * 768 + 512 + h * 32 + d];
        }
        __syncthreads();
        if (act) {
            for (int kk = kg; kk < cnt; kk += 8) {
                const float4* krow = reinterpret_cast<const float4*>(&Ks[kk][0]);
                float s = 0.f;
                #pragma unroll
                for (int d4 = 0; d4 < 8; ++d4) {
                    const float4 kv = krow[d4];
                    s += qreg[d4 * 4 + 0] * kv.x + qreg[d4 * 4 + 1] * kv.y
                       + qreg[d4 * 4 + 2] * kv.z + qreg[d4 * 4 + 3] * kv.w;
                }
                s *= scale;
                const float4* vrow = reinterpret_cast<const float4*>(&Vs[kk][0]);
                if (s <= m) {
                    const float e = __expf(s - m);
                    l += e;
                    #pragma unroll
                    for (int d4 = 0; d4 < 8; ++d4) {
                        const float4 vv = vrow[d4];
                        o[d4 * 4 + 0] += e * vv.x; o[d4 * 4 + 1] += e * vv.y;
                        o[d4 * 4 + 2] += e * vv.z; o[d4 * 4 + 3] += e * vv.w;
                    }
                } else {
                    const float c = __expf(m - s);
                    l = l * c + 1.f;
                    #pragma unroll
                    for (int d4 = 0; d4 < 8; ++d4) {
                        const float4 vv = vrow[d4];
                        o[d4 * 4 + 0] = o[d4 * 4 + 0] * c + vv.x;
                        o[d4 * 4 + 1] = o[d4 * 4 + 1] * c + vv.y;
                        o[d4 * 4 + 2] = o[d4 * 4 + 2] * c + vv.z;
                        o[d4 * 4 + 3] = o[d4 * 4 + 3] * c + vv.w;
                    }
                    m = s;
                }
            }
        }
    }
    __shared__ float pm[32][8];
    __shared__ float pl[32][8];
    __shared__ float po[8][32][33];
    pm[ql][kg] = m; pl[ql][kg] = l;
    #pragma unroll
    for (int d = 0; d < 32; ++d) po[kg][d][ql] = o[d];
    __syncthreads();
    if (kg == 0) {
        float M = pm[ql][0];
        #pragma unroll
        for (int i = 1; i < 8; ++i) M = fmaxf(M, pm[ql][i]);
        float L = 0.f;
        #pragma unroll
        for (int i = 0; i < 8; ++i) L += pl[ql][i] * __expf(pm[ql][i] - M);
        const float invL = 1.f / L;
        #pragma unroll
        for (int i = 0; i < 8; ++i) pm[ql][i] = __expf(pm[ql][i] - M) * invL;
    }
    __syncthreads();
    if (act) {
        #pragma unroll
        for (int dd = 0; dd < 4; ++dd) {
            const int d = kg * 4 + dd;
            float v = 0.f;
            #pragma unroll
            for (int i = 0; i < 8; ++i) v += pm[ql][i] * po[i][d][ql];
            outp[((size_t)b * 300 + q) * 256 + h * 32 + d] = f2bf(v);
        }
    }
}

// ---------------- LN block-reduce body ----------------
#define LN_BODY(vexpr, widx)                                                  \
    const int row = blockIdx.x, t = threadIdx.x, z = blockIdx.y;              \
    (void)z;                                                                  \
    const int i = row * 256 + t;                                              \
    const float v = (vexpr);                                                  \
    __shared__ float r1[4], r2[4];                                            \
    float s = v;                                                              \
    _Pragma("unroll")                                                         \
    for (int o = 32; o; o >>= 1) s += __shfl_xor(s, o);                       \
    if ((t & 63) == 0) r1[t >> 6] = s;                                        \
    __syncthreads();                                                          \
    const float mean = (r1[0] + r1[1] + r1[2] + r1[3]) * (1.f / 256.f);       \
    const float dd = v - mean;                                                \
    float sq = dd * dd;                                                       \
    _Pragma("unroll")                                                         \
    for (int o = 32; o; o >>= 1) sq += __shfl_xor(sq, o);                     \
    if ((t & 63) == 0) r2[t >> 6] = sq;                                       \
    __syncthreads();                                                          \
    const float var = (r2[0] + r2[1] + r2[2] + r2[3]) * (1.f / 256.f);        \
    const float y = dd * rsqrtf(var + 1e-5f) * ln_w[(widx) * 256 + t]         \
                    + ln_b[(widx) * 256 + t];

// norm2 + qc=bf16(y+pos) + tgt2T (z=1 only)
__global__ __launch_bounds__(256) void ln2_fused(
    const float* __restrict__ presum, const float* __restrict__ pos0,
    const float* __restrict__ pos1, const float* __restrict__ ln_w,
    const float* __restrict__ ln_b, short* __restrict__ qc_bf,
    float* __restrict__ tgt2T)
{
    LN_BODY(presum[(size_t)z * STOK + i], z * 3 + 1)
    const float* pos = z ? pos1 : pos0;
    qc_bf[(size_t)z * STOK + i] = f2bf(y + pos[i]);
    if (z == 1) tgt2T[i] = y;
}

// norm1: z=0: LN(tgt2T+out2); z=1: LN(tgt2T+out2+out3); writes bf16 + fp32
__global__ __launch_bounds__(256) void ln1_fused(
    const float* __restrict__ tgt2T, const float* __restrict__ out2,
    const float* __restrict__ out3, const float* __restrict__ ln_w,
    const float* __restrict__ ln_b, short* __restrict__ ln1b,
    float* __restrict__ ln1f)
{
    LN_BODY(tgt2T[row * 256 + t] + out2[row * 256 + t] + (z ? out3[row * 256 + t] : 0.f), z * 3 + 0)
    ln1b[(size_t)z * STOK + i] = f2bf(y);
    ln1f[(size_t)z * STOK + i] = y;
}

// norm3: final outputs
__global__ __launch_bounds__(256) void ln3_kernel(
    const float* __restrict__ ffny, const float* __restrict__ ln_w,
    const float* __restrict__ ln_b, float* __restrict__ o0,
    float* __restrict__ o1)
{
    LN_BODY(ffny[(size_t)z * STOK + i], z * 3 + 2)
    (z ? o1 : o0)[i] = y;
}

// ---------------- deformable sampling + fused softmax, bf16 value ----------------
__global__ __launch_bounds__(256) void sample_kernel(
    const short* __restrict__ valb, const float* __restrict__ offb,
    const float* __restrict__ awb, const float* __restrict__ ref0,
    const float* __restrict__ ref1, short* __restrict__ out)
{
    const int HL[4] = {100, 50, 25, 13};
    const int WL[4] = {134, 67, 34, 17};
    const int ST[4] = {0, 13400, 16750, 17600};
    const int z = blockIdx.y;
    const int bq = blockIdx.x;
    const int b = bq / 300;
    const int t = threadIdx.x, h = t >> 5, d = t & 31;
    const float* offp = offb + (size_t)z * STOK + (size_t)bq * 256;
    const float* awp  = awb + (size_t)z * NTOK * 128 + (size_t)bq * 128 + h * 16;
    const float* refp = (z ? ref1 : ref0) + (size_t)bq * 8;
    const short* vb = valb + (size_t)z * MVAL * 256 + (size_t)b * LTOT_C * 256;

    // fused softmax over the 16 logits of this head (redundant per lane)
    float w16[16];
    float mx = -1e30f;
    #pragma unroll
    for (int i = 0; i < 16; ++i) { w16[i] = awp[i]; mx = fmaxf(mx, w16[i]); }
    float ssum = 0.f;
    #pragma unroll
    for (int i = 0; i < 16; ++i) { w16[i] = __expf(w16[i] - mx); ssum += w16[i]; }
    const float sinv = 1.f / ssum;

    float acc = 0.f;
    #pragma unroll
    for (int l = 0; l < 4; ++l) {
        const float Wf = (float)WL[l], Hf = (float)HL[l];
        const float rx = refp[l * 2], ry = refp[l * 2 + 1];
        #pragma unroll
        for (int p = 0; p < 4; ++p) {
            const int oidx = ((h * 4 + l) * 4 + p) * 2;
            const float px = (rx + offp[oidx]     / Wf) * Wf - 0.5f;
            const float py = (ry + offp[oidx + 1] / Hf) * Hf - 0.5f;
            const float wgt = w16[l * 4 + p] * sinv;
            const float x0f = floorf(px), y0f = floorf(py);
            const float wx = px - x0f, wy = py - y0f;
            const int x0 = (int)x0f, y0 = (int)y0f;
            float v00 = 0.f, v10 = 0.f, v01 = 0.f, v11 = 0.f;
            const bool xin0 = (x0 >= 0) & (x0 < WL[l]);
            const bool xin1 = (x0 + 1 >= 0) & (x0 + 1 < WL[l]);
            if (y0 >= 0 && y0 < HL[l]) {
                if (xin0) v00 = bf2f(vb[(size_t)(ST[l] + y0 * WL[l] + x0) * 256 + h * 32 + d]);
                if (xin1) v10 = bf2f(vb[(size_t)(ST[l] + y0 * WL[l] + x0 + 1) * 256 + h * 32 + d]);
            }
            if (y0 + 1 >= 0 && y0 + 1 < HL[l]) {
                if (xin0) v01 = bf2f(vb[(size_t)(ST[l] + (y0 + 1) * WL[l] + x0) * 256 + h * 32 + d]);
                if (xin1) v11 = bf2f(vb[(size_t)(ST[l] + (y0 + 1) * WL[l] + x0 + 1) * 256 + h * 32 + d]);
            }
            acc += wgt * (v00 * (1.f - wx) * (1.f - wy) + v10 * wx * (1.f - wy)
                        + v01 * (1.f - wx) * wy + v11 * wx * wy);
        }
    }
    out[(size_t)z * STOK + (size_t)bq * 256 + t] = f2bf(acc);
}

extern "C" void kernel_launch(void* const* d_in, const int* in_sizes, int n_in,
                              void* d_out, int out_size, void* d_ws, size_t ws_size,
                              hipStream_t stream) {
    const float* tgt[2] = {(const float*)d_in[0], (const float*)d_in[1]};
    const float* pos[2] = {(const float*)d_in[2], (const float*)d_in[3]};
    const float* ref[2] = {(const float*)d_in[4], (const float*)d_in[5]};
    const float* src[2] = {(const float*)d_in[6], (const float*)d_in[7]};
    const float* sa_in_w  = (const float*)d_in[8];
    const float* sa_in_b  = (const float*)d_in[9];
    const float* sa_out_w = (const float*)d_in[10];
    const float* sa_out_b = (const float*)d_in[11];
    const float* ln_w = (const float*)d_in[12];
    const float* ln_b = (const float*)d_in[13];
    const float* ffn_w1 = (const float*)d_in[14];
    const float* ffn_b1 = (const float*)d_in[15];
    const float* ffn_w2 = (const float*)d_in[16];
    const float* ffn_b2 = (const float*)d_in[17];
    const float* val_w = (const float*)d_in[18];
    const float* val_b = (const float*)d_in[19];
    const float* off_w = (const float*)d_in[20];
    const float* off_b = (const float*)d_in[21];
    const float* aw_w = (const float*)d_in[22];
    const float* aw_b = (const float*)d_in[23];
    const float* cout_w = (const float*)d_in[24];
    const float* cout_b = (const float*)d_in[25];

    char* base = (char*)d_ws;
    size_t off = 0;
    auto alloc = [&](size_t bytes) -> char* {
        char* p = base + off;
        off += (bytes + 255) & ~(size_t)255;
        return p;
    };
    short* wbf   = (short*)alloc(2031616 * 2);
    short* qb_bf = (short*)alloc((size_t)2 * STOK * 2);
    short* tgtb  = (short*)alloc((size_t)2 * STOK * 2);
    float* qkv   = (float*)alloc((size_t)2 * 921600 * 4);
    short* attno = (short*)alloc((size_t)2 * STOK * 2);
    float* presum= (float*)alloc((size_t)2 * STOK * 4);
    short* qc_bf = (short*)alloc((size_t)2 * STOK * 2);
    float* tgt2T = (float*)alloc((size_t)STOK * 4);
    float* offb  = (float*)alloc((size_t)2 * STOK * 4);
    float* awb   = (float*)alloc((size_t)2 * NTOK * 128 * 4);
    short* valb  = (short*)alloc((size_t)2 * MVAL * 256 * 2);
    short* samp  = (short*)alloc((size_t)2 * STOK * 2);
    short* ln1b  = (short*)alloc((size_t)2 * STOK * 2);
    float* ln1f  = (float*)alloc((size_t)2 * STOK * 4);
    short* ffnh  = (short*)alloc((size_t)2 * NTOK * 1024 * 2);
    float* ffny  = (float*)alloc((size_t)2 * STOK * 4);

    // weight sub-offsets (elements)
    short* sa_in_bf  = wbf + 0;        // 393216
    short* sa_out_bf = wbf + 393216;   // 131072
    short* ffn1_bf   = wbf + 524288;   // 524288
    short* ffn2_bf   = wbf + 1048576;  // 524288
    short* val_bf    = wbf + 1572864;  // 131072
    short* off_bf    = wbf + 1703936;  // 131072
    short* aw_bf     = wbf + 1835008;  // 65536
    short* cout_bf   = wbf + 1900544;  // 131072

    float* out0 = (float*)d_out;
    float* out1 = out0 + STOK;
    float* out2 = out1 + STOK;   // F_RGB = t2_RGB
    float* out3 = out2 + STOK;   // F_T

    const dim3 b256(256);

    // 1. weights -> bf16
    WcvtArgs wa;
    wa.s[0] = sa_in_w;  wa.d[0] = sa_in_bf;  wa.n[0] = 393216;
    wa.s[1] = sa_out_w; wa.d[1] = sa_out_bf; wa.n[1] = 131072;
    wa.s[2] = ffn_w1;   wa.d[2] = ffn1_bf;   wa.n[2] = 524288;
    wa.s[3] = ffn_w2;   wa.d[3] = ffn2_bf;   wa.n[3] = 524288;
    wa.s[4] = val_w;    wa.d[4] = val_bf;    wa.n[4] = 131072;
    wa.s[5] = off_w;    wa.d[5] = off_bf;    wa.n[5] = 131072;
    wa.s[6] = aw_w;     wa.d[6] = aw_bf;     wa.n[6] = 65536;
    wa.s[7] = cout_w;   wa.d[7] = cout_bf;   wa.n[7] = 131072;
    wcvt<<<dim3(256, 8), b256, 0, stream>>>(wa);

    // 2. activation prep
    prep_act<<<dim3(150, 2), b256, 0, stream>>>(tgt[0], tgt[1], pos[0], pos[1], qb_bf, tgtb);

    // 3. value projections (big): src fp32 -> bf16 val.  val z=0 <- src_T
    gemm_bf16<true, false, false, true><<<dim3(2, 557, 1), b256, 0, stream>>>(
        src[1], 0, 256, val_bf, 0, 256, val_b, 0, nullptr, nullptr, 0,
        valb, 0, 256, MVAL, 256);
    gemm_bf16<true, false, false, true><<<dim3(2, 557, 1), b256, 0, stream>>>(
        src[0], 0, 256, val_bf + 65536, 0, 256, val_b + 256, 0, nullptr, nullptr, 0,
        valb + (size_t)MVAL * 256, 0, 256, MVAL, 256);

    // 4. in-proj qk (N=512) and v (N=256) -> qkv fp32 [z][1200][768]
    gemm_bf16<false, false, false, false><<<dim3(4, 10, 2), b256, 0, stream>>>(
        qb_bf, (size_t)STOK, 256, sa_in_bf, 196608, 256, sa_in_b, 768,
        nullptr, nullptr, 0, qkv, 921600, 768, NTOK, 256);
    gemm_bf16<false, false, false, false><<<dim3(2, 10, 2), b256, 0, stream>>>(
        tgtb, (size_t)STOK, 256, sa_in_bf + 512 * 256, 196608, 256, sa_in_b + 512, 768,
        nullptr, nullptr, 0, qkv + 512, 921600, 768, NTOK, 256);

    // 5. attention -> attno bf16
    attn2_kernel<<<dim3(10, 32, 2), b256, 0, stream>>>(qkv, attno);

    // 6. out-proj + residual(tgt) -> presum fp32
    gemm_bf16<false, true, false, false><<<dim3(2, 10, 2), b256, 0, stream>>>(
        attno, (size_t)STOK, 256, sa_out_bf, 65536, 256, sa_out_b, 256,
        tgt[0], tgt[1], 256, presum, (size_t)STOK, 256, NTOK, 256);

    // 7. norm2 + qc=bf16(LN+pos) + tgt2T
    ln2_fused<<<dim3(NTOK, 2), b256, 0, stream>>>(presum, pos[0], pos[1], ln_w, ln_b, qc_bf, tgt2T);

    // 8. offsets / aw logits
    gemm_bf16<false, false, false, false><<<dim3(2, 10, 2), b256, 0, stream>>>(
        qc_bf, (size_t)STOK, 256, off_bf, 65536, 256, off_b, 256,
        nullptr, nullptr, 0, offb, (size_t)STOK, 256, NTOK, 256);
    gemm_bf16<false, false, false, false><<<dim3(1, 10, 2), b256, 0, stream>>>(
        qc_bf, (size_t)STOK, 256, aw_bf, 32768, 256, aw_b, 128,
        nullptr, nullptr, 0, awb, (size_t)NTOK * 128, 128, NTOK, 256);

    // 9. sampling (fused softmax) -> samp bf16
    sample_kernel<<<dim3(NTOK, 2), b256, 0, stream>>>(valb, offb, awb, ref[0], ref[1], samp);

    // 10. cout -> out2/out3 (t2_RGB / t2_T)
    gemm_bf16<false, false, false, false><<<dim3(2, 10, 2), b256, 0, stream>>>(
        samp, (size_t)STOK, 256, cout_bf, 65536, 256, cout_b, 256,
        nullptr, nullptr, 0, out2, (size_t)STOK, 256, NTOK, 256);

    // 11. norm1 (cross residuals fused)
    ln1_fused<<<dim3(NTOK, 2), b256, 0, stream>>>(tgt2T, out2, out3, ln_w, ln_b, ln1b, ln1f);

    // 12. FFN1 (ReLU, bf16 out)
    gemm_bf16<false, false, true, true><<<dim3(8, 10, 2), b256, 0, stream>>>(
        ln1b, (size_t)STOK, 256, ffn1_bf, 262144, 256, ffn_b1, 1024,
        nullptr, nullptr, 0, ffnh, (size_t)NTOK * 1024, 1024, NTOK, 256);

    // 13. FFN2 + residual(ln1f) -> ffny fp32
    gemm_bf16<false, true, false, false><<<dim3(2, 10, 2), b256, 0, stream>>>(
        ffnh, (size_t)NTOK * 1024, 1024, ffn2_bf, 262144, 1024, ffn_b2, 256,
        ln1f, ln1f + STOK, 256, ffny, (size_t)STOK, 256, NTOK, 1024);

    // 14. norm3 -> out0/out1
    ln3_kernel<<<dim3(NTOK, 2), b256, 0, stream>>>(ffny, ln_w, ln_b, out0, out1);
}

// Round 4
// 259.725 us; speedup vs baseline: 3.8033x; 1.3820x over previous
//
#include <hip/hip_runtime.h>
#include <cstddef>
#include <math.h>

#define NTOK 1200          // B*NQ = 4*300
#define LTOT_C 17821
#define MVAL 71284         // B*LTOT
#define STOK (NTOK * 256)  // 307200

typedef __attribute__((ext_vector_type(8))) short bhalf8;
typedef __attribute__((ext_vector_type(4))) float f32x4;

static __device__ __forceinline__ short f2bf(float f) {
    unsigned u = __builtin_bit_cast(unsigned, f);
    u += 0x7fffu + ((u >> 16) & 1u);   // RNE
    return (short)(u >> 16);
}
static __device__ __forceinline__ float bf2f(short s) {
    unsigned u = ((unsigned)(unsigned short)s) << 16;
    return __builtin_bit_cast(float, u);
}
static __device__ __forceinline__ bhalf8 cvt8(float4 a, float4 b) {
    bhalf8 h;
    h[0] = f2bf(a.x); h[1] = f2bf(a.y); h[2] = f2bf(a.z); h[3] = f2bf(a.w);
    h[4] = f2bf(b.x); h[5] = f2bf(b.y); h[6] = f2bf(b.z); h[7] = f2bf(b.w);
    return h;
}

// ---------------- weight convert fp32 -> bf16 (10 tasks) ----------------
struct WcvtArgs { const float* s[10]; short* d[10]; int n[10]; };
__global__ __launch_bounds__(256) void wcvt(WcvtArgs a) {
    const int ti = blockIdx.y;
    const float* s = a.s[ti];
    short* d = a.d[ti];
    const int n = a.n[ti];
    for (int base = (blockIdx.x * 256 + threadIdx.x) * 8; base < n; base += gridDim.x * 256 * 8) {
        const float4 f0 = *reinterpret_cast<const float4*>(s + base);
        const float4 f1 = *reinterpret_cast<const float4*>(s + base + 4);
        *reinterpret_cast<bhalf8*>(d + base) = cvt8(f0, f1);
    }
}

// ---------------- activation prep: qb=bf16(tgt+pos), tgtb=bf16(tgt), bias concat ----------------
__global__ __launch_bounds__(256) void prep_act(
    const float* __restrict__ tgt0, const float* __restrict__ tgt1,
    const float* __restrict__ pos0, const float* __restrict__ pos1,
    short* __restrict__ qb_bf, short* __restrict__ tgtb,
    const float* __restrict__ off_b, const float* __restrict__ aw_b,
    float* __restrict__ baw)
{
    const int z = blockIdx.y;
    if (blockIdx.x == 0 && z == 0) {
        for (int i = threadIdx.x; i < 768; i += 256) {
            const int zz = i / 384, j = i - zz * 384;
            baw[i] = (j < 256) ? off_b[zz * 256 + j] : aw_b[zz * 128 + (j - 256)];
        }
    }
    const float* tg = z ? tgt1 : tgt0;
    const float* ps = z ? pos1 : pos0;
    const int base = (blockIdx.x * 256 + threadIdx.x) * 8;
    if (base >= STOK) return;
    const float4 t0 = *reinterpret_cast<const float4*>(tg + base);
    const float4 t1 = *reinterpret_cast<const float4*>(tg + base + 4);
    const float4 p0 = *reinterpret_cast<const float4*>(ps + base);
    const float4 p1 = *reinterpret_cast<const float4*>(ps + base + 4);
    float4 s0 = make_float4(t0.x + p0.x, t0.y + p0.y, t0.z + p0.z, t0.w + p0.w);
    float4 s1 = make_float4(t1.x + p1.x, t1.y + p1.y, t1.z + p1.z, t1.w + p1.w);
    *reinterpret_cast<bhalf8*>(qb_bf + (size_t)z * STOK + base) = cvt8(s0, s1);
    *reinterpret_cast<bhalf8*>(tgtb + (size_t)z * STOK + base) = cvt8(t0, t1);
}

// ---------------- unified bf16 MFMA GEMM ----------------
// C = act( A[M,K] @ W[N,K]^T + bias (+Res) );  tile 128x128, 4 waves (2x2), BK=64
// If Av1 != null: z=0 uses Av, z=1 uses Av1 (aStrideZ ignored).
template<bool A_FP32, bool HASRES, bool RELU, bool OUT_BF16>
__global__ __launch_bounds__(256) void gemm_bf16(
    const void* __restrict__ Av, const void* __restrict__ Av1, size_t aStrideZ, int lda,
    const short* __restrict__ Wv, size_t wStrideZ, int ldw,
    const float* __restrict__ bias, size_t biasStrideZ,
    const float* __restrict__ Res0, const float* __restrict__ Res1, int ldr,
    void* __restrict__ Cv, size_t cStrideZ, int ldc,
    int M, int K)
{
    __shared__ short As[128 * 64];
    __shared__ short Bs[128 * 64];
    const int z = blockIdx.z;
    const void* Asel = (Av1 != nullptr && z == 1) ? Av1 : Av;
    const size_t zoff = (Av1 != nullptr) ? 0 : (size_t)z * aStrideZ;
    const short* W = Wv + (size_t)z * wStrideZ;
    const float* bz = bias + (size_t)z * biasStrideZ;
    const int t = threadIdx.x;
    const int wave = t >> 6, lane = t & 63;
    const int l15 = lane & 15, l4 = lane >> 4;
    const int wr = wave >> 1, wc = wave & 1;
    const int bm = blockIdx.y * 128, bn = blockIdx.x * 128;
    f32x4 acc[4][4] = {};

    for (int k0 = 0; k0 < K; k0 += 64) {
        __syncthreads();
        #pragma unroll
        for (int i = 0; i < 4; ++i) {
            const int G = t + i * 256;
            const int m = G >> 3, g = G & 7;
            const int row = bm + m;
            bhalf8 h;
            #pragma unroll
            for (int q = 0; q < 8; ++q) h[q] = 0;
            if (A_FP32) {
                if (row < M) {
                    const float* s = (const float*)Asel + zoff + (size_t)row * lda + k0 + g * 8;
                    h = cvt8(*reinterpret_cast<const float4*>(s),
                             *reinterpret_cast<const float4*>(s + 4));
                }
            } else {
                if (row < M)
                    h = *reinterpret_cast<const bhalf8*>((const short*)Asel + zoff + (size_t)row * lda + k0 + g * 8);
            }
            *reinterpret_cast<bhalf8*>(&As[m * 64 + ((g ^ (m & 7)) << 3)]) = h;
            const bhalf8 hb = *reinterpret_cast<const bhalf8*>(W + (size_t)(bn + m) * ldw + k0 + g * 8);
            *reinterpret_cast<bhalf8*>(&Bs[m * 64 + ((g ^ (m & 7)) << 3)]) = hb;
        }
        __syncthreads();
        #pragma unroll
        for (int kf = 0; kf < 2; ++kf) {
            bhalf8 af[4], bfv[4];
            #pragma unroll
            for (int mf = 0; mf < 4; ++mf) {
                const int m = (wr << 6) + (mf << 4) + l15;
                const int g = ((kf << 2) + l4) ^ (m & 7);
                af[mf] = *reinterpret_cast<const bhalf8*>(&As[m * 64 + (g << 3)]);
            }
            #pragma unroll
            for (int nf = 0; nf < 4; ++nf) {
                const int n = (wc << 6) + (nf << 4) + l15;
                const int g = ((kf << 2) + l4) ^ (n & 7);
                bfv[nf] = *reinterpret_cast<const bhalf8*>(&Bs[n * 64 + (g << 3)]);
            }
            #pragma unroll
            for (int mf = 0; mf < 4; ++mf)
                #pragma unroll
                for (int nf = 0; nf < 4; ++nf)
                    acc[mf][nf] = __builtin_amdgcn_mfma_f32_16x16x32_bf16(
                        af[mf], bfv[nf], acc[mf][nf], 0, 0, 0);
        }
    }
    const float* Rz = HASRES ? (z ? Res1 : Res0) : nullptr;
    float br[4];
    #pragma unroll
    for (int nf = 0; nf < 4; ++nf) br[nf] = bz[bn + (wc << 6) + (nf << 4) + l15];
    #pragma unroll
    for (int mf = 0; mf < 4; ++mf) {
        #pragma unroll
        for (int j = 0; j < 4; ++j) {
            const int row = bm + (wr << 6) + (mf << 4) + (l4 << 2) + j;
            if (row >= M) continue;
            const int colbase = bn + (wc << 6);
            #pragma unroll
            for (int nf = 0; nf < 4; ++nf) {
                const int col = colbase + (nf << 4) + l15;
                float v = acc[mf][nf][j] + br[nf];
                if (HASRES) v += Rz[(size_t)row * ldr + col];
                if (RELU) v = fmaxf(v, 0.f);
                if (OUT_BF16)
                    ((short*)Cv + (size_t)z * cStrideZ)[(size_t)row * ldc + col] = f2bf(v);
                else
                    ((float*)Cv + (size_t)z * cStrideZ)[(size_t)row * ldc + col] = v;
            }
        }
    }
}

// ---------------- self-attention: key-parallel online softmax, bf16 out ----------------
__global__ __launch_bounds__(256) void attn2_kernel(
    const float* __restrict__ qkv_base, short* __restrict__ out_base)
{
    const float scale = 0.17677669529663687f;  // 1/sqrt(32)
    const float* qkv = qkv_base + (size_t)blockIdx.z * 921600;
    short* outp = out_base + (size_t)blockIdx.z * STOK;
    const int b = blockIdx.y >> 3, h = blockIdx.y & 7;
    const int t = threadIdx.x;
    const int ql = t & 31;
    const int kg = t >> 5;
    const int q = blockIdx.x * 32 + ql;
    const bool act = q < 300;
    const float* base = qkv + (size_t)b * 300 * 768;

    float qreg[32];
    if (act) {
        const float4* qp = reinterpret_cast<const float4*>(base + (size_t)q * 768 + h * 32);
        #pragma unroll
        for (int d4 = 0; d4 < 8; ++d4) {
            const float4 v = qp[d4];
            qreg[d4 * 4 + 0] = v.x; qreg[d4 * 4 + 1] = v.y;
            qreg[d4 * 4 + 2] = v.z; qreg[d4 * 4 + 3] = v.w;
        }
    }
    __shared__ float Ks[64][32];
    __shared__ float Vs[64][32];
    float m = -1e30f, l = 0.f, o[32];
    #pragma unroll
    for (int d = 0; d < 32; ++d) o[d] = 0.f;

    for (int k0 = 0; k0 < 300; k0 += 64) {
        const int cnt = min(64, 300 - k0);
        __syncthreads();
        for (int i = t; i < cnt * 32; i += 256) {
            const int kr = i >> 5, d = i & 31;
            Ks[kr][d] = base[(size_t)(k0 + kr) * 768 + 256 + h * 32 + d];
            Vs[kr][d] = base[(size_t)(k0 + kr) * 768 + 512 + h * 32 + d];
        }
        __syncthreads();
        if (act) {
            for (int kk = kg; kk < cnt; kk += 8) {
                const float4* krow = reinterpret_cast<const float4*>(&Ks[kk][0]);
                float s = 0.f;
                #pragma unroll
                for (int d4 = 0; d4 < 8; ++d4) {
                    const float4 kv = krow[d4];
                    s += qreg[d4 * 4 + 0] * kv.x + qreg[d4 * 4 + 1] * kv.y
                       + qreg[d4 * 4 + 2] * kv.z + qreg[d4 * 4 + 3] * kv.w;
                }
                s *= scale;
                const float4* vrow = reinterpret_cast<const float4*>(&Vs[kk][0]);
                if (s <= m) {
                    const float e = __expf(s - m);
                    l += e;
                    #pragma unroll
                    for (int d4 = 0; d4 < 8; ++d4) {
                        const float4 vv = vrow[d4];
                        o[d4 * 4 + 0] += e * vv.x; o[d4 * 4 + 1] += e * vv.y;
                        o[d4 * 4 + 2] += e * vv.z; o[d4 * 4 + 3] += e * vv.w;
                    }
                } else {
                    const float c = __expf(m - s);
                    l = l * c + 1.f;
                    #pragma unroll
                    for (int d4 = 0; d4 < 8; ++d4) {
                        const float4 vv = vrow[d4];
                        o[d4 * 4 + 0] = o[d4 * 4 + 0] * c + vv.x;
                        o[d4 * 4 + 1] = o[d4 * 4 + 1] * c + vv.y;
                        o[d4 * 4 + 2] = o[d4 * 4 + 2] * c + vv.z;
                        o[d4 * 4 + 3] = o[d4 * 4 + 3] * c + vv.w;
                    }
                    m = s;
                }
            }
        }
    }
    __shared__ float pm[32][8];
    __shared__ float pl[32][8];
    __shared__ float po[8][32][33];
    pm[ql][kg] = m; pl[ql][kg] = l;
    #pragma unroll
    for (int d = 0; d < 32; ++d) po[kg][d][ql] = o[d];
    __syncthreads();
    if (kg == 0) {
        float M = pm[ql][0];
        #pragma unroll
        for (int i = 1; i < 8; ++i) M = fmaxf(M, pm[ql][i]);
        float L = 0.f;
        #pragma unroll
        for (int i = 0; i < 8; ++i) L += pl[ql][i] * __expf(pm[ql][i] - M);
        const float invL = 1.f / L;
        #pragma unroll
        for (int i = 0; i < 8; ++i) pm[ql][i] = __expf(pm[ql][i] - M) * invL;
    }
    __syncthreads();
    if (act) {
        #pragma unroll
        for (int dd = 0; dd < 4; ++dd) {
            const int d = kg * 4 + dd;
            float v = 0.f;
            #pragma unroll
            for (int i = 0; i < 8; ++i) v += pm[ql][i] * po[i][d][ql];
            outp[((size_t)b * 300 + q) * 256 + h * 32 + d] = f2bf(v);
        }
    }
}

// ---------------- LN block-reduce body ----------------
#define LN_BODY(vexpr, widx)                                                  \
    const int row = blockIdx.x, t = threadIdx.x, z = blockIdx.y;              \
    (void)z;                                                                  \
    const int i = row * 256 + t;                                              \
    const float v = (vexpr);                                                  \
    __shared__ float r1[4], r2[4];                                            \
    float s = v;                                                              \
    _Pragma("unroll")                                                         \
    for (int o = 32; o; o >>= 1) s += __shfl_xor(s, o);                       \
    if ((t & 63) == 0) r1[t >> 6] = s;                                        \
    __syncthreads();                                                          \
    const float mean = (r1[0] + r1[1] + r1[2] + r1[3]) * (1.f / 256.f);       \
    const float dd = v - mean;                                                \
    float sq = dd * dd;                                                       \
    _Pragma("unroll")                                                         \
    for (int o = 32; o; o >>= 1) sq += __shfl_xor(sq, o);                     \
    if ((t & 63) == 0) r2[t >> 6] = sq;                                       \
    __syncthreads();                                                          \
    const float var = (r2[0] + r2[1] + r2[2] + r2[3]) * (1.f / 256.f);        \
    const float y = dd * rsqrtf(var + 1e-5f) * ln_w[(widx) * 256 + t]         \
                    + ln_b[(widx) * 256 + t];

// norm2 + qc=bf16(y+pos) + tgt2T (z=1 only)
__global__ __launch_bounds__(256) void ln2_fused(
    const float* __restrict__ presum, const float* __restrict__ pos0,
    const float* __restrict__ pos1, const float* __restrict__ ln_w,
    const float* __restrict__ ln_b, short* __restrict__ qc_bf,
    float* __restrict__ tgt2T)
{
    LN_BODY(presum[(size_t)z * STOK + i], z * 3 + 1)
    const float* pos = z ? pos1 : pos0;
    qc_bf[(size_t)z * STOK + i] = f2bf(y + pos[i]);
    if (z == 1) tgt2T[i] = y;
}

// norm1: z=0: LN(tgt2T+out2); z=1: LN(tgt2T+out2+out3); writes bf16 + fp32
__global__ __launch_bounds__(256) void ln1_fused(
    const float* __restrict__ tgt2T, const float* __restrict__ out2,
    const float* __restrict__ out3, const float* __restrict__ ln_w,
    const float* __restrict__ ln_b, short* __restrict__ ln1b,
    float* __restrict__ ln1f)
{
    LN_BODY(tgt2T[row * 256 + t] + out2[row * 256 + t] + (z ? out3[row * 256 + t] : 0.f), z * 3 + 0)
    ln1b[(size_t)z * STOK + i] = f2bf(y);
    ln1f[(size_t)z * STOK + i] = y;
}

// norm3: final outputs
__global__ __launch_bounds__(256) void ln3_kernel(
    const float* __restrict__ ffny, const float* __restrict__ ln_w,
    const float* __restrict__ ln_b, float* __restrict__ o0,
    float* __restrict__ o1)
{
    LN_BODY(ffny[(size_t)z * STOK + i], z * 3 + 2)
    (z ? o1 : o0)[i] = y;
}

// ---------------- deformable sampling v2: short4 gathers, wave=(q, head-half) ----------------
// grid (600, 2); block 256 = 4 waves = 2 queries x 2 head-halves.
// lane = pp(1b) | h4(2b) | dl(3b): pp = point-half, h = hh*4+h4, d-range = dl*4..dl*4+3
__global__ __launch_bounds__(256) void sample_kernel(
    const short* __restrict__ valb, const float* __restrict__ oaw,
    const float* __restrict__ ref0, const float* __restrict__ ref1,
    short* __restrict__ out)
{
    const int HL[4] = {100, 50, 25, 13};
    const int WL[4] = {134, 67, 34, 17};
    const int ST[4] = {0, 13400, 16750, 17600};
    const int z = blockIdx.y;
    const int t = threadIdx.x;
    const int wave = t >> 6, lane = t & 63;
    const int qi = wave >> 1, hh = wave & 1;
    const int pp = lane >> 5, h4 = (lane >> 3) & 3, dl = lane & 7;
    const int h = hh * 4 + h4;
    const int bq = blockIdx.x * 2 + qi;
    const int b = bq / 300;
    const float* op = oaw + ((size_t)z * NTOK + bq) * 384;
    const float* offp = op + h * 32;        // [l][p][2]
    const float* awp  = op + 256 + h * 16;  // [l][p]
    const float* refp = (z ? ref1 : ref0) + (size_t)bq * 8;
    const short* vb = valb + (size_t)z * MVAL * 256 + (size_t)b * LTOT_C * 256;
    const int co = h * 32 + dl * 4;

    float w16[16];
    float mx = -1e30f;
    #pragma unroll
    for (int i = 0; i < 16; ++i) { w16[i] = awp[i]; mx = fmaxf(mx, w16[i]); }
    float ssum = 0.f;
    #pragma unroll
    for (int i = 0; i < 16; ++i) { w16[i] = __expf(w16[i] - mx); ssum += w16[i]; }
    const float sinv = 1.f / ssum;

    float a0 = 0.f, a1 = 0.f, a2 = 0.f, a3 = 0.f;
#define TAP(cond, ridx, wv)                                                   \
    if (cond) {                                                               \
        const short4 sv = *reinterpret_cast<const short4*>(                   \
            vb + (size_t)(ridx) * 256 + co);                                  \
        a0 += (wv) * bf2f(sv.x); a1 += (wv) * bf2f(sv.y);                     \
        a2 += (wv) * bf2f(sv.z); a3 += (wv) * bf2f(sv.w);                     \
    }
    #pragma unroll
    for (int l = 0; l < 4; ++l) {
        const int Wl = WL[l], Hl = HL[l];
        const float rx = refp[l * 2] * (float)Wl - 0.5f;
        const float ry = refp[l * 2 + 1] * (float)Hl - 0.5f;
        #pragma unroll
        for (int j = 0; j < 2; ++j) {
            const int p = pp * 2 + j;
            const float px = rx + offp[(l * 4 + p) * 2];
            const float py = ry + offp[(l * 4 + p) * 2 + 1];
            const float wgt = w16[l * 4 + p] * sinv;
            const float x0f = floorf(px), y0f = floorf(py);
            const float wx = px - x0f, wy = py - y0f;
            const int x0 = (int)x0f, y0 = (int)y0f;
            const bool xa = (x0 >= 0) & (x0 < Wl);
            const bool xb = (x0 >= -1) & (x0 < Wl - 1);
            const bool ya = (y0 >= 0) & (y0 < Hl);
            const bool yb = (y0 >= -1) & (y0 < Hl - 1);
            const int rbase = ST[l] + y0 * Wl + x0;
            const float w00 = wgt * (1.f - wx) * (1.f - wy);
            const float w10 = wgt * wx * (1.f - wy);
            const float w01 = wgt * (1.f - wx) * wy;
            const float w11 = wgt * wx * wy;
            TAP(ya & xa, rbase, w00)
            TAP(ya & xb, rbase + 1, w10)
            TAP(yb & xa, rbase + Wl, w01)
            TAP(yb & xb, rbase + Wl + 1, w11)
        }
    }
#undef TAP
    a0 += __shfl_xor(a0, 32);
    a1 += __shfl_xor(a1, 32);
    a2 += __shfl_xor(a2, 32);
    a3 += __shfl_xor(a3, 32);
    if (pp == 0) {
        short4 o;
        o.x = f2bf(a0); o.y = f2bf(a1); o.z = f2bf(a2); o.w = f2bf(a3);
        *reinterpret_cast<short4*>(&out[((size_t)z * NTOK + bq) * 256 + co]) = o;
    }
}

extern "C" void kernel_launch(void* const* d_in, const int* in_sizes, int n_in,
                              void* d_out, int out_size, void* d_ws, size_t ws_size,
                              hipStream_t stream) {
    const float* tgt[2] = {(const float*)d_in[0], (const float*)d_in[1]};
    const float* pos[2] = {(const float*)d_in[2], (const float*)d_in[3]};
    const float* ref[2] = {(const float*)d_in[4], (const float*)d_in[5]};
    const float* src[2] = {(const float*)d_in[6], (const float*)d_in[7]};
    const float* sa_in_w  = (const float*)d_in[8];
    const float* sa_in_b  = (const float*)d_in[9];
    const float* sa_out_w = (const float*)d_in[10];
    const float* sa_out_b = (const float*)d_in[11];
    const float* ln_w = (const float*)d_in[12];
    const float* ln_b = (const float*)d_in[13];
    const float* ffn_w1 = (const float*)d_in[14];
    const float* ffn_b1 = (const float*)d_in[15];
    const float* ffn_w2 = (const float*)d_in[16];
    const float* ffn_b2 = (const float*)d_in[17];
    const float* val_w = (const float*)d_in[18];
    const float* val_b = (const float*)d_in[19];
    const float* off_w = (const float*)d_in[20];
    const float* off_b = (const float*)d_in[21];
    const float* aw_w = (const float*)d_in[22];
    const float* aw_b = (const float*)d_in[23];
    const float* cout_w = (const float*)d_in[24];
    const float* cout_b = (const float*)d_in[25];

    char* base = (char*)d_ws;
    size_t off = 0;
    auto alloc = [&](size_t bytes) -> char* {
        char* p = base + off;
        off += (bytes + 255) & ~(size_t)255;
        return p;
    };
    short* wbf   = (short*)alloc((size_t)2031616 * 2);
    float* baw   = (float*)alloc(768 * 4);
    short* qb_bf = (short*)alloc((size_t)2 * STOK * 2);
    short* tgtb  = (short*)alloc((size_t)2 * STOK * 2);
    float* qkv   = (float*)alloc((size_t)2 * 921600 * 4);
    short* attno = (short*)alloc((size_t)2 * STOK * 2);
    float* presum= (float*)alloc((size_t)2 * STOK * 4);
    short* qc_bf = (short*)alloc((size_t)2 * STOK * 2);
    float* tgt2T = (float*)alloc((size_t)STOK * 4);
    float* oawb  = (float*)alloc((size_t)2 * NTOK * 384 * 4);
    short* valb  = (short*)alloc((size_t)2 * MVAL * 256 * 2);
    short* samp  = (short*)alloc((size_t)2 * STOK * 2);
    short* ln1b  = (short*)alloc((size_t)2 * STOK * 2);
    float* ln1f  = (float*)alloc((size_t)2 * STOK * 4);
    short* ffnh  = (short*)alloc((size_t)2 * NTOK * 1024 * 2);
    float* ffny  = (float*)alloc((size_t)2 * STOK * 4);

    // weight sub-offsets (elements)
    short* sa_in_bf  = wbf + 0;        // 393216
    short* sa_out_bf = wbf + 393216;   // 131072
    short* ffn1_bf   = wbf + 524288;   // 524288
    short* ffn2_bf   = wbf + 1048576;  // 524288
    short* val_bf    = wbf + 1572864;  // 131072
    short* cout_bf   = wbf + 1703936;  // 131072
    short* oaw_bf    = wbf + 1835008;  // 196608 = 2 x (off 65536 + aw 32768)

    float* out0 = (float*)d_out;
    float* out1 = out0 + STOK;
    float* out2 = out1 + STOK;   // F_RGB = t2_RGB
    float* out3 = out2 + STOK;   // F_T

    const dim3 b256(256);

    // 1. weights -> bf16 (off/aw concatenated per z)
    WcvtArgs wa;
    wa.s[0] = sa_in_w;        wa.d[0] = sa_in_bf;       wa.n[0] = 393216;
    wa.s[1] = sa_out_w;       wa.d[1] = sa_out_bf;      wa.n[1] = 131072;
    wa.s[2] = ffn_w1;         wa.d[2] = ffn1_bf;        wa.n[2] = 524288;
    wa.s[3] = ffn_w2;         wa.d[3] = ffn2_bf;        wa.n[3] = 524288;
    wa.s[4] = val_w;          wa.d[4] = val_bf;         wa.n[4] = 131072;
    wa.s[5] = cout_w;         wa.d[5] = cout_bf;        wa.n[5] = 131072;
    wa.s[6] = off_w;          wa.d[6] = oaw_bf;         wa.n[6] = 65536;
    wa.s[7] = aw_w;           wa.d[7] = oaw_bf + 65536; wa.n[7] = 32768;
    wa.s[8] = off_w + 65536;  wa.d[8] = oaw_bf + 98304; wa.n[8] = 65536;
    wa.s[9] = aw_w + 32768;   wa.d[9] = oaw_bf + 163840;wa.n[9] = 32768;
    wcvt<<<dim3(128, 10), b256, 0, stream>>>(wa);

    // 2. activation prep + bias concat
    prep_act<<<dim3(150, 2), b256, 0, stream>>>(tgt[0], tgt[1], pos[0], pos[1],
                                                qb_bf, tgtb, off_b, aw_b, baw);

    // 3. value projections (z-batched): z=0 <- src_T, z=1 <- src_RGB
    gemm_bf16<true, false, false, true><<<dim3(2, 557, 2), b256, 0, stream>>>(
        src[1], src[0], 0, 256, val_bf, 65536, 256, val_b, 256, nullptr, nullptr, 0,
        valb, (size_t)MVAL * 256, 256, MVAL, 256);

    // 4. in-proj qk (N=512) and v (N=256) -> qkv fp32 [z][1200][768]
    gemm_bf16<false, false, false, false><<<dim3(4, 10, 2), b256, 0, stream>>>(
        qb_bf, nullptr, (size_t)STOK, 256, sa_in_bf, 196608, 256, sa_in_b, 768,
        nullptr, nullptr, 0, qkv, 921600, 768, NTOK, 256);
    gemm_bf16<false, false, false, false><<<dim3(2, 10, 2), b256, 0, stream>>>(
        tgtb, nullptr, (size_t)STOK, 256, sa_in_bf + 512 * 256, 196608, 256, sa_in_b + 512, 768,
        nullptr, nullptr, 0, qkv + 512, 921600, 768, NTOK, 256);

    // 5. attention -> attno bf16
    attn2_kernel<<<dim3(10, 32, 2), b256, 0, stream>>>(qkv, attno);

    // 6. out-proj + residual(tgt) -> presum fp32
    gemm_bf16<false, true, false, false><<<dim3(2, 10, 2), b256, 0, stream>>>(
        attno, nullptr, (size_t)STOK, 256, sa_out_bf, 65536, 256, sa_out_b, 256,
        tgt[0], tgt[1], 256, presum, (size_t)STOK, 256, NTOK, 256);

    // 7. norm2 + qc=bf16(LN+pos) + tgt2T
    ln2_fused<<<dim3(NTOK, 2), b256, 0, stream>>>(presum, pos[0], pos[1], ln_w, ln_b, qc_bf, tgt2T);

    // 8. fused offsets+aw logits (N=384) -> oawb
    gemm_bf16<false, false, false, false><<<dim3(3, 10, 2), b256, 0, stream>>>(
        qc_bf, nullptr, (size_t)STOK, 256, oaw_bf, 98304, 256, baw, 384,
        nullptr, nullptr, 0, oawb, (size_t)NTOK * 384, 384, NTOK, 256);

    // 9. sampling (fused softmax) -> samp bf16
    sample_kernel<<<dim3(600, 2), b256, 0, stream>>>(valb, oawb, ref[0], ref[1], samp);

    // 10. cout -> out2/out3 (t2_RGB / t2_T)
    gemm_bf16<false, false, false, false><<<dim3(2, 10, 2), b256, 0, stream>>>(
        samp, nullptr, (size_t)STOK, 256, cout_bf, 65536, 256, cout_b, 256,
        nullptr, nullptr, 0, out2, (size_t)STOK, 256, NTOK, 256);

    // 11. norm1 (cross residuals fused)
    ln1_fused<<<dim3(NTOK, 2), b256, 0, stream>>>(tgt2T, out2, out3, ln_w, ln_b, ln1b, ln1f);

    // 12. FFN1 (ReLU, bf16 out)
    gemm_bf16<false, false, true, true><<<dim3(8, 10, 2), b256, 0, stream>>>(
        ln1b, nullptr, (size_t)STOK, 256, ffn1_bf, 262144, 256, ffn_b1, 1024,
        nullptr, nullptr, 0, ffnh, (size_t)NTOK * 1024, 1024, NTOK, 256);

    // 13. FFN2 + residual(ln1f) -> ffny fp32
    gemm_bf16<false, true, false, false><<<dim3(2, 10, 2), b256, 0, stream>>>(
        ffnh, nullptr, (size_t)NTOK * 1024, 1024, ffn2_bf, 262144, 1024, ffn_b2, 256,
        ln1f, ln1f + STOK, 256, ffny, (size_t)STOK, 256, NTOK, 1024);

    // 14. norm3 -> out0/out1
    ln3_kernel<<<dim3(NTOK, 2), b256, 0, stream>>>(ffny, ln_w, ln_b, out0, out1);
}

// Round 5
// 213.667 us; speedup vs baseline: 4.6231x; 1.2156x over previous
//
#include <hip/hip_runtime.h>
#include <cstddef>
#include <math.h>

#define NTOK 1200          // B*NQ = 4*300
#define LTOT_C 17821
#define MVAL 71284         // B*LTOT
#define STOK (NTOK * 256)  // 307200

typedef __attribute__((ext_vector_type(8))) short bhalf8;
typedef __attribute__((ext_vector_type(4))) float f32x4;

static __device__ __forceinline__ short f2bf(float f) {
    unsigned u = __builtin_bit_cast(unsigned, f);
    u += 0x7fffu + ((u >> 16) & 1u);   // RNE
    return (short)(u >> 16);
}
static __device__ __forceinline__ float bf2f(short s) {
    unsigned u = ((unsigned)(unsigned short)s) << 16;
    return __builtin_bit_cast(float, u);
}
static __device__ __forceinline__ bhalf8 cvt8(float4 a, float4 b) {
    bhalf8 h;
    h[0] = f2bf(a.x); h[1] = f2bf(a.y); h[2] = f2bf(a.z); h[3] = f2bf(a.w);
    h[4] = f2bf(b.x); h[5] = f2bf(b.y); h[6] = f2bf(b.z); h[7] = f2bf(b.w);
    return h;
}

// ---------------- weight convert fp32 -> bf16 (10 tasks) ----------------
struct WcvtArgs { const float* s[10]; short* d[10]; int n[10]; };
__global__ __launch_bounds__(256) void wcvt(WcvtArgs a) {
    const int ti = blockIdx.y;
    const float* s = a.s[ti];
    short* d = a.d[ti];
    const int n = a.n[ti];
    for (int base = (blockIdx.x * 256 + threadIdx.x) * 8; base < n; base += gridDim.x * 256 * 8) {
        const float4 f0 = *reinterpret_cast<const float4*>(s + base);
        const float4 f1 = *reinterpret_cast<const float4*>(s + base + 4);
        *reinterpret_cast<bhalf8*>(d + base) = cvt8(f0, f1);
    }
}

// ---------------- activation prep: qb=bf16(tgt+pos), tgtb=bf16(tgt), bias concat ----------------
__global__ __launch_bounds__(256) void prep_act(
    const float* __restrict__ tgt0, const float* __restrict__ tgt1,
    const float* __restrict__ pos0, const float* __restrict__ pos1,
    short* __restrict__ qb_bf, short* __restrict__ tgtb,
    const float* __restrict__ off_b, const float* __restrict__ aw_b,
    float* __restrict__ baw)
{
    const int z = blockIdx.y;
    if (blockIdx.x == 0 && z == 0) {
        for (int i = threadIdx.x; i < 768; i += 256) {
            const int zz = i / 384, j = i - zz * 384;
            baw[i] = (j < 256) ? off_b[zz * 256 + j] : aw_b[zz * 128 + (j - 256)];
        }
    }
    const float* tg = z ? tgt1 : tgt0;
    const float* ps = z ? pos1 : pos0;
    const int base = (blockIdx.x * 256 + threadIdx.x) * 8;
    if (base >= STOK) return;
    const float4 t0 = *reinterpret_cast<const float4*>(tg + base);
    const float4 t1 = *reinterpret_cast<const float4*>(tg + base + 4);
    const float4 p0 = *reinterpret_cast<const float4*>(ps + base);
    const float4 p1 = *reinterpret_cast<const float4*>(ps + base + 4);
    float4 s0 = make_float4(t0.x + p0.x, t0.y + p0.y, t0.z + p0.z, t0.w + p0.w);
    float4 s1 = make_float4(t1.x + p1.x, t1.y + p1.y, t1.z + p1.z, t1.w + p1.w);
    *reinterpret_cast<bhalf8*>(qb_bf + (size_t)z * STOK + base) = cvt8(s0, s1);
    *reinterpret_cast<bhalf8*>(tgtb + (size_t)z * STOK + base) = cvt8(t0, t1);
}

// ---------------- unified bf16 MFMA GEMM, software-pipelined ----------------
// C = act( A[M,K] @ W[N,K]^T + bias (+Res) );  tile BM x 128, 4 waves (2x2), BK=64
// Prefetch: issue K-step k+1 global loads into regs during compute of step k.
// If Av1 != null: z=0 uses Av, z=1 uses Av1 (aStrideZ ignored).
template<bool A_FP32, bool HASRES, bool RELU, bool OUT_BF16, int BM>
__global__ __launch_bounds__(256) void gemm_bf16(
    const void* __restrict__ Av, const void* __restrict__ Av1, size_t aStrideZ, int lda,
    const short* __restrict__ Wv, size_t wStrideZ, int ldw,
    const float* __restrict__ bias, size_t biasStrideZ,
    const float* __restrict__ Res0, const float* __restrict__ Res1, int ldr,
    void* __restrict__ Cv, size_t cStrideZ, int ldc,
    int M, int K)
{
    constexpr int AIT = BM / 32;   // A staging iterations (256 thr x 8 elems each)
    constexpr int MFR = BM / 32;   // m-fragments per wave (wave covers BM/2 rows)
    __shared__ short As[BM * 64];
    __shared__ short Bs[128 * 64];
    const int z = blockIdx.z;
    const void* Asel = (Av1 != nullptr && z == 1) ? Av1 : Av;
    const size_t zoff = (Av1 != nullptr) ? 0 : (size_t)z * aStrideZ;
    const short* W = Wv + (size_t)z * wStrideZ;
    const float* bz = bias + (size_t)z * biasStrideZ;
    const int t = threadIdx.x;
    const int wave = t >> 6, lane = t & 63;
    const int l15 = lane & 15, l4 = lane >> 4;
    const int wr = wave >> 1, wc = wave & 1;
    const int bm = blockIdx.y * BM, bn = blockIdx.x * 128;
    f32x4 acc[MFR][4] = {};

    float4 paf[AIT][2];   // A prefetch (fp32 path)
    bhalf8 pab[AIT];      // A prefetch (bf16 path)
    bhalf8 pwb[4];        // W prefetch
    const int NK = K >> 6;

    auto issue = [&](int k0) {
        #pragma unroll
        for (int i = 0; i < AIT; ++i) {
            const int G = t + i * 256;
            const int m = G >> 3, g = G & 7;
            const int row = bm + m;
            if (A_FP32) {
                if (row < M) {
                    const float* s = (const float*)Asel + zoff + (size_t)row * lda + k0 + g * 8;
                    paf[i][0] = *reinterpret_cast<const float4*>(s);
                    paf[i][1] = *reinterpret_cast<const float4*>(s + 4);
                } else {
                    paf[i][0] = make_float4(0.f, 0.f, 0.f, 0.f);
                    paf[i][1] = make_float4(0.f, 0.f, 0.f, 0.f);
                }
            } else {
                if (row < M) {
                    pab[i] = *reinterpret_cast<const bhalf8*>(
                        (const short*)Asel + zoff + (size_t)row * lda + k0 + g * 8);
                } else {
                    #pragma unroll
                    for (int q = 0; q < 8; ++q) pab[i][q] = 0;
                }
            }
        }
        #pragma unroll
        for (int i = 0; i < 4; ++i) {
            const int G = t + i * 256;
            const int n = G >> 3, g = G & 7;
            pwb[i] = *reinterpret_cast<const bhalf8*>(W + (size_t)(bn + n) * ldw + k0 + g * 8);
        }
    };
    auto commit = [&]() {
        #pragma unroll
        for (int i = 0; i < AIT; ++i) {
            const int G = t + i * 256;
            const int m = G >> 3, g = G & 7;
            bhalf8 h;
            if (A_FP32) h = cvt8(paf[i][0], paf[i][1]);
            else h = pab[i];
            *reinterpret_cast<bhalf8*>(&As[m * 64 + ((g ^ (m & 7)) << 3)]) = h;
        }
        #pragma unroll
        for (int i = 0; i < 4; ++i) {
            const int G = t + i * 256;
            const int n = G >> 3, g = G & 7;
            *reinterpret_cast<bhalf8*>(&Bs[n * 64 + ((g ^ (n & 7)) << 3)]) = pwb[i];
        }
    };
    auto compute = [&]() {
        #pragma unroll
        for (int kf = 0; kf < 2; ++kf) {
            bhalf8 af[MFR], bfv[4];
            #pragma unroll
            for (int mf = 0; mf < MFR; ++mf) {
                const int m = wr * (BM / 2) + (mf << 4) + l15;
                const int g = ((kf << 2) + l4) ^ (m & 7);
                af[mf] = *reinterpret_cast<const bhalf8*>(&As[m * 64 + (g << 3)]);
            }
            #pragma unroll
            for (int nf = 0; nf < 4; ++nf) {
                const int n = (wc << 6) + (nf << 4) + l15;
                const int g = ((kf << 2) + l4) ^ (n & 7);
                bfv[nf] = *reinterpret_cast<const bhalf8*>(&Bs[n * 64 + (g << 3)]);
            }
            #pragma unroll
            for (int mf = 0; mf < MFR; ++mf)
                #pragma unroll
                for (int nf = 0; nf < 4; ++nf)
                    acc[mf][nf] = __builtin_amdgcn_mfma_f32_16x16x32_bf16(
                        af[mf], bfv[nf], acc[mf][nf], 0, 0, 0);
        }
    };

    issue(0);
    commit();
    for (int ks = 0; ks < NK; ++ks) {
        __syncthreads();
        if (ks + 1 < NK) issue((ks + 1) << 6);
        compute();
        __syncthreads();
        if (ks + 1 < NK) commit();
    }

    const float* Rz = HASRES ? (z ? Res1 : Res0) : nullptr;
    float br[4];
    #pragma unroll
    for (int nf = 0; nf < 4; ++nf) br[nf] = bz[bn + (wc << 6) + (nf << 4) + l15];
    #pragma unroll
    for (int mf = 0; mf < MFR; ++mf) {
        #pragma unroll
        for (int j = 0; j < 4; ++j) {
            const int row = bm + wr * (BM / 2) + (mf << 4) + (l4 << 2) + j;
            if (row >= M) continue;
            const int colbase = bn + (wc << 6);
            #pragma unroll
            for (int nf = 0; nf < 4; ++nf) {
                const int col = colbase + (nf << 4) + l15;
                float v = acc[mf][nf][j] + br[nf];
                if (HASRES) v += Rz[(size_t)row * ldr + col];
                if (RELU) v = fmaxf(v, 0.f);
                if (OUT_BF16)
                    ((short*)Cv + (size_t)z * cStrideZ)[(size_t)row * ldc + col] = f2bf(v);
                else
                    ((float*)Cv + (size_t)z * cStrideZ)[(size_t)row * ldc + col] = v;
            }
        }
    }
}

// ---------------- self-attention: key-parallel online softmax, bf16 out ----------------
__global__ __launch_bounds__(256) void attn2_kernel(
    const float* __restrict__ qkv_base, short* __restrict__ out_base)
{
    const float scale = 0.17677669529663687f;  // 1/sqrt(32)
    const float* qkv = qkv_base + (size_t)blockIdx.z * 921600;
    short* outp = out_base + (size_t)blockIdx.z * STOK;
    const int b = blockIdx.y >> 3, h = blockIdx.y & 7;
    const int t = threadIdx.x;
    const int ql = t & 31;
    const int kg = t >> 5;
    const int q = blockIdx.x * 32 + ql;
    const bool act = q < 300;
    const float* base = qkv + (size_t)b * 300 * 768;

    float qreg[32];
    if (act) {
        const float4* qp = reinterpret_cast<const float4*>(base + (size_t)q * 768 + h * 32);
        #pragma unroll
        for (int d4 = 0; d4 < 8; ++d4) {
            const float4 v = qp[d4];
            qreg[d4 * 4 + 0] = v.x; qreg[d4 * 4 + 1] = v.y;
            qreg[d4 * 4 + 2] = v.z; qreg[d4 * 4 + 3] = v.w;
        }
    }
    __shared__ float Ks[64][32];
    __shared__ float Vs[64][32];
    float m = -1e30f, l = 0.f, o[32];
    #pragma unroll
    for (int d = 0; d < 32; ++d) o[d] = 0.f;

    for (int k0 = 0; k0 < 300; k0 += 64) {
        const int cnt = min(64, 300 - k0);
        __syncthreads();
        for (int i = t; i < cnt * 32; i += 256) {
            const int kr = i >> 5, d = i & 31;
            Ks[kr][d] = base[(size_t)(k0 + kr) * 768 + 256 + h * 32 + d];
            Vs[kr][d] = base[(size_t)(k0 + kr) * 768 + 512 + h * 32 + d];
        }
        __syncthreads();
        if (act) {
            for (int kk = kg; kk < cnt; kk += 8) {
                const float4* krow = reinterpret_cast<const float4*>(&Ks[kk][0]);
                float s = 0.f;
                #pragma unroll
                for (int d4 = 0; d4 < 8; ++d4) {
                    const float4 kv = krow[d4];
                    s += qreg[d4 * 4 + 0] * kv.x + qreg[d4 * 4 + 1] * kv.y
                       + qreg[d4 * 4 + 2] * kv.z + qreg[d4 * 4 + 3] * kv.w;
                }
                s *= scale;
                const float4* vrow = reinterpret_cast<const float4*>(&Vs[kk][0]);
                if (s <= m) {
                    const float e = __expf(s - m);
                    l += e;
                    #pragma unroll
                    for (int d4 = 0; d4 < 8; ++d4) {
                        const float4 vv = vrow[d4];
                        o[d4 * 4 + 0] += e * vv.x; o[d4 * 4 + 1] += e * vv.y;
                        o[d4 * 4 + 2] += e * vv.z; o[d4 * 4 + 3] += e * vv.w;
                    }
                } else {
                    const float c = __expf(m - s);
                    l = l * c + 1.f;
                    #pragma unroll
                    for (int d4 = 0; d4 < 8; ++d4) {
                        const float4 vv = vrow[d4];
                        o[d4 * 4 + 0] = o[d4 * 4 + 0] * c + vv.x;
                        o[d4 * 4 + 1] = o[d4 * 4 + 1] * c + vv.y;
                        o[d4 * 4 + 2] = o[d4 * 4 + 2] * c + vv.z;
                        o[d4 * 4 + 3] = o[d4 * 4 + 3] * c + vv.w;
                    }
                    m = s;
                }
            }
        }
    }
    __shared__ float pm[32][8];
    __shared__ float pl[32][8];
    __shared__ float po[8][32][33];
    pm[ql][kg] = m; pl[ql][kg] = l;
    #pragma unroll
    for (int d = 0; d < 32; ++d) po[kg][d][ql] = o[d];
    __syncthreads();
    if (kg == 0) {
        float M = pm[ql][0];
        #pragma unroll
        for (int i = 1; i < 8; ++i) M = fmaxf(M, pm[ql][i]);
        float L = 0.f;
        #pragma unroll
        for (int i = 0; i < 8; ++i) L += pl[ql][i] * __expf(pm[ql][i] - M);
        const float invL = 1.f / L;
        #pragma unroll
        for (int i = 0; i < 8; ++i) pm[ql][i] = __expf(pm[ql][i] - M) * invL;
    }
    __syncthreads();
    if (act) {
        #pragma unroll
        for (int dd = 0; dd < 4; ++dd) {
            const int d = kg * 4 + dd;
            float v = 0.f;
            #pragma unroll
            for (int i = 0; i < 8; ++i) v += pm[ql][i] * po[i][d][ql];
            outp[((size_t)b * 300 + q) * 256 + h * 32 + d] = f2bf(v);
        }
    }
}

// ---------------- LN block-reduce body ----------------
#define LN_BODY(vexpr, widx)                                                  \
    const int row = blockIdx.x, t = threadIdx.x, z = blockIdx.y;              \
    (void)z;                                                                  \
    const int i = row * 256 + t;                                              \
    const float v = (vexpr);                                                  \
    __shared__ float r1[4], r2[4];                                            \
    float s = v;                                                              \
    _Pragma("unroll")                                                         \
    for (int o = 32; o; o >>= 1) s += __shfl_xor(s, o);                       \
    if ((t & 63) == 0) r1[t >> 6] = s;                                        \
    __syncthreads();                                                          \
    const float mean = (r1[0] + r1[1] + r1[2] + r1[3]) * (1.f / 256.f);       \
    const float dd = v - mean;                                                \
    float sq = dd * dd;                                                       \
    _Pragma("unroll")                                                         \
    for (int o = 32; o; o >>= 1) sq += __shfl_xor(sq, o);                     \
    if ((t & 63) == 0) r2[t >> 6] = sq;                                       \
    __syncthreads();                                                          \
    const float var = (r2[0] + r2[1] + r2[2] + r2[3]) * (1.f / 256.f);        \
    const float y = dd * rsqrtf(var + 1e-5f) * ln_w[(widx) * 256 + t]         \
                    + ln_b[(widx) * 256 + t];

// norm2 + qc=bf16(y+pos) + tgt2T (z=1 only)
__global__ __launch_bounds__(256) void ln2_fused(
    const float* __restrict__ presum, const float* __restrict__ pos0,
    const float* __restrict__ pos1, const float* __restrict__ ln_w,
    const float* __restrict__ ln_b, short* __restrict__ qc_bf,
    float* __restrict__ tgt2T)
{
    LN_BODY(presum[(size_t)z * STOK + i], z * 3 + 1)
    const float* pos = z ? pos1 : pos0;
    qc_bf[(size_t)z * STOK + i] = f2bf(y + pos[i]);
    if (z == 1) tgt2T[i] = y;
}

// norm1: z=0: LN(tgt2T+out2); z=1: LN(tgt2T+out2+out3); writes bf16 + fp32
__global__ __launch_bounds__(256) void ln1_fused(
    const float* __restrict__ tgt2T, const float* __restrict__ out2,
    const float* __restrict__ out3, const float* __restrict__ ln_w,
    const float* __restrict__ ln_b, short* __restrict__ ln1b,
    float* __restrict__ ln1f)
{
    LN_BODY(tgt2T[row * 256 + t] + out2[row * 256 + t] + (z ? out3[row * 256 + t] : 0.f), z * 3 + 0)
    ln1b[(size_t)z * STOK + i] = f2bf(y);
    ln1f[(size_t)z * STOK + i] = y;
}

// norm3: final outputs
__global__ __launch_bounds__(256) void ln3_kernel(
    const float* __restrict__ ffny, const float* __restrict__ ln_w,
    const float* __restrict__ ln_b, float* __restrict__ o0,
    float* __restrict__ o1)
{
    LN_BODY(ffny[(size_t)z * STOK + i], z * 3 + 2)
    (z ? o1 : o0)[i] = y;
}

// ---------------- deformable sampling v2: short4 gathers, wave=(q, head-half) ----------------
__global__ __launch_bounds__(256) void sample_kernel(
    const short* __restrict__ valb, const float* __restrict__ oaw,
    const float* __restrict__ ref0, const float* __restrict__ ref1,
    short* __restrict__ out)
{
    const int HL[4] = {100, 50, 25, 13};
    const int WL[4] = {134, 67, 34, 17};
    const int ST[4] = {0, 13400, 16750, 17600};
    const int z = blockIdx.y;
    const int t = threadIdx.x;
    const int wave = t >> 6, lane = t & 63;
    const int qi = wave >> 1, hh = wave & 1;
    const int pp = lane >> 5, h4 = (lane >> 3) & 3, dl = lane & 7;
    const int h = hh * 4 + h4;
    const int bq = blockIdx.x * 2 + qi;
    const int b = bq / 300;
    const float* op = oaw + ((size_t)z * NTOK + bq) * 384;
    const float* offp = op + h * 32;
    const float* awp  = op + 256 + h * 16;
    const float* refp = (z ? ref1 : ref0) + (size_t)bq * 8;
    const short* vb = valb + (size_t)z * MVAL * 256 + (size_t)b * LTOT_C * 256;
    const int co = h * 32 + dl * 4;

    float w16[16];
    float mx = -1e30f;
    #pragma unroll
    for (int i = 0; i < 16; ++i) { w16[i] = awp[i]; mx = fmaxf(mx, w16[i]); }
    float ssum = 0.f;
    #pragma unroll
    for (int i = 0; i < 16; ++i) { w16[i] = __expf(w16[i] - mx); ssum += w16[i]; }
    const float sinv = 1.f / ssum;

    float a0 = 0.f, a1 = 0.f, a2 = 0.f, a3 = 0.f;
#define TAP(cond, ridx, wv)                                                   \
    if (cond) {                                                               \
        const short4 sv = *reinterpret_cast<const short4*>(                   \
            vb + (size_t)(ridx) * 256 + co);                                  \
        a0 += (wv) * bf2f(sv.x); a1 += (wv) * bf2f(sv.y);                     \
        a2 += (wv) * bf2f(sv.z); a3 += (wv) * bf2f(sv.w);                     \
    }
    #pragma unroll
    for (int l = 0; l < 4; ++l) {
        const int Wl = WL[l], Hl = HL[l];
        const float rx = refp[l * 2] * (float)Wl - 0.5f;
        const float ry = refp[l * 2 + 1] * (float)Hl - 0.5f;
        #pragma unroll
        for (int j = 0; j < 2; ++j) {
            const int p = pp * 2 + j;
            const float px = rx + offp[(l * 4 + p) * 2];
            const float py = ry + offp[(l * 4 + p) * 2 + 1];
            const float wgt = w16[l * 4 + p] * sinv;
            const float x0f = floorf(px), y0f = floorf(py);
            const float wx = px - x0f, wy = py - y0f;
            const int x0 = (int)x0f, y0 = (int)y0f;
            const bool xa = (x0 >= 0) & (x0 < Wl);
            const bool xb = (x0 >= -1) & (x0 < Wl - 1);
            const bool ya = (y0 >= 0) & (y0 < Hl);
            const bool yb = (y0 >= -1) & (y0 < Hl - 1);
            const int rbase = ST[l] + y0 * Wl + x0;
            const float w00 = wgt * (1.f - wx) * (1.f - wy);
            const float w10 = wgt * wx * (1.f - wy);
            const float w01 = wgt * (1.f - wx) * wy;
            const float w11 = wgt * wx * wy;
            TAP(ya & xa, rbase, w00)
            TAP(ya & xb, rbase + 1, w10)
            TAP(yb & xa, rbase + Wl, w01)
            TAP(yb & xb, rbase + Wl + 1, w11)
        }
    }
#undef TAP
    a0 += __shfl_xor(a0, 32);
    a1 += __shfl_xor(a1, 32);
    a2 += __shfl_xor(a2, 32);
    a3 += __shfl_xor(a3, 32);
    if (pp == 0) {
        short4 o;
        o.x = f2bf(a0); o.y = f2bf(a1); o.z = f2bf(a2); o.w = f2bf(a3);
        *reinterpret_cast<short4*>(&out[((size_t)z * NTOK + bq) * 256 + co]) = o;
    }
}

extern "C" void kernel_launch(void* const* d_in, const int* in_sizes, int n_in,
                              void* d_out, int out_size, void* d_ws, size_t ws_size,
                              hipStream_t stream) {
    const float* tgt[2] = {(const float*)d_in[0], (const float*)d_in[1]};
    const float* pos[2] = {(const float*)d_in[2], (const float*)d_in[3]};
    const float* ref[2] = {(const float*)d_in[4], (const float*)d_in[5]};
    const float* src[2] = {(const float*)d_in[6], (const float*)d_in[7]};
    const float* sa_in_w  = (const float*)d_in[8];
    const float* sa_in_b  = (const float*)d_in[9];
    const float* sa_out_w = (const float*)d_in[10];
    const float* sa_out_b = (const float*)d_in[11];
    const float* ln_w = (const float*)d_in[12];
    const float* ln_b = (const float*)d_in[13];
    const float* ffn_w1 = (const float*)d_in[14];
    const float* ffn_b1 = (const float*)d_in[15];
    const float* ffn_w2 = (const float*)d_in[16];
    const float* ffn_b2 = (const float*)d_in[17];
    const float* val_w = (const float*)d_in[18];
    const float* val_b = (const float*)d_in[19];
    const float* off_w = (const float*)d_in[20];
    const float* off_b = (const float*)d_in[21];
    const float* aw_w = (const float*)d_in[22];
    const float* aw_b = (const float*)d_in[23];
    const float* cout_w = (const float*)d_in[24];
    const float* cout_b = (const float*)d_in[25];

    char* base = (char*)d_ws;
    size_t off = 0;
    auto alloc = [&](size_t bytes) -> char* {
        char* p = base + off;
        off += (bytes + 255) & ~(size_t)255;
        return p;
    };
    short* wbf   = (short*)alloc((size_t)2031616 * 2);
    float* baw   = (float*)alloc(768 * 4);
    short* qb_bf = (short*)alloc((size_t)2 * STOK * 2);
    short* tgtb  = (short*)alloc((size_t)2 * STOK * 2);
    float* qkv   = (float*)alloc((size_t)2 * 921600 * 4);
    short* attno = (short*)alloc((size_t)2 * STOK * 2);
    float* presum= (float*)alloc((size_t)2 * STOK * 4);
    short* qc_bf = (short*)alloc((size_t)2 * STOK * 2);
    float* tgt2T = (float*)alloc((size_t)STOK * 4);
    float* oawb  = (float*)alloc((size_t)2 * NTOK * 384 * 4);
    short* valb  = (short*)alloc((size_t)2 * MVAL * 256 * 2);
    short* samp  = (short*)alloc((size_t)2 * STOK * 2);
    short* ln1b  = (short*)alloc((size_t)2 * STOK * 2);
    float* ln1f  = (float*)alloc((size_t)2 * STOK * 4);
    short* ffnh  = (short*)alloc((size_t)2 * NTOK * 1024 * 2);
    float* ffny  = (float*)alloc((size_t)2 * STOK * 4);

    // weight sub-offsets (elements)
    short* sa_in_bf  = wbf + 0;        // 393216
    short* sa_out_bf = wbf + 393216;   // 131072
    short* ffn1_bf   = wbf + 524288;   // 524288
    short* ffn2_bf   = wbf + 1048576;  // 524288
    short* val_bf    = wbf + 1572864;  // 131072
    short* cout_bf   = wbf + 1703936;  // 131072
    short* oaw_bf    = wbf + 1835008;  // 196608 = 2 x (off 65536 + aw 32768)

    float* out0 = (float*)d_out;
    float* out1 = out0 + STOK;
    float* out2 = out1 + STOK;   // F_RGB = t2_RGB
    float* out3 = out2 + STOK;   // F_T

    const dim3 b256(256);

    // 1. weights -> bf16 (off/aw concatenated per z)
    WcvtArgs wa;
    wa.s[0] = sa_in_w;        wa.d[0] = sa_in_bf;       wa.n[0] = 393216;
    wa.s[1] = sa_out_w;       wa.d[1] = sa_out_bf;      wa.n[1] = 131072;
    wa.s[2] = ffn_w1;         wa.d[2] = ffn1_bf;        wa.n[2] = 524288;
    wa.s[3] = ffn_w2;         wa.d[3] = ffn2_bf;        wa.n[3] = 524288;
    wa.s[4] = val_w;          wa.d[4] = val_bf;         wa.n[4] = 131072;
    wa.s[5] = cout_w;         wa.d[5] = cout_bf;        wa.n[5] = 131072;
    wa.s[6] = off_w;          wa.d[6] = oaw_bf;         wa.n[6] = 65536;
    wa.s[7] = aw_w;           wa.d[7] = oaw_bf + 65536; wa.n[7] = 32768;
    wa.s[8] = off_w + 65536;  wa.d[8] = oaw_bf + 98304; wa.n[8] = 65536;
    wa.s[9] = aw_w + 32768;   wa.d[9] = oaw_bf + 163840;wa.n[9] = 32768;
    wcvt<<<dim3(128, 10), b256, 0, stream>>>(wa);

    // 2. activation prep + bias concat
    prep_act<<<dim3(150, 2), b256, 0, stream>>>(tgt[0], tgt[1], pos[0], pos[1],
                                                qb_bf, tgtb, off_b, aw_b, baw);

    // 3. value projections (z-batched, pipelined): z=0 <- src_T, z=1 <- src_RGB
    gemm_bf16<true, false, false, true, 128><<<dim3(2, 557, 2), b256, 0, stream>>>(
        src[1], src[0], 0, 256, val_bf, 65536, 256, val_b, 256, nullptr, nullptr, 0,
        valb, (size_t)MVAL * 256, 256, MVAL, 256);

    // 4. in-proj qk (N=512) and v (N=256) -> qkv fp32 [z][1200][768]
    gemm_bf16<false, false, false, false, 64><<<dim3(4, 19, 2), b256, 0, stream>>>(
        qb_bf, nullptr, (size_t)STOK, 256, sa_in_bf, 196608, 256, sa_in_b, 768,
        nullptr, nullptr, 0, qkv, 921600, 768, NTOK, 256);
    gemm_bf16<false, false, false, false, 64><<<dim3(2, 19, 2), b256, 0, stream>>>(
        tgtb, nullptr, (size_t)STOK, 256, sa_in_bf + 512 * 256, 196608, 256, sa_in_b + 512, 768,
        nullptr, nullptr, 0, qkv + 512, 921600, 768, NTOK, 256);

    // 5. attention -> attno bf16
    attn2_kernel<<<dim3(10, 32, 2), b256, 0, stream>>>(qkv, attno);

    // 6. out-proj + residual(tgt) -> presum fp32
    gemm_bf16<false, true, false, false, 64><<<dim3(2, 19, 2), b256, 0, stream>>>(
        attno, nullptr, (size_t)STOK, 256, sa_out_bf, 65536, 256, sa_out_b, 256,
        tgt[0], tgt[1], 256, presum, (size_t)STOK, 256, NTOK, 256);

    // 7. norm2 + qc=bf16(LN+pos) + tgt2T
    ln2_fused<<<dim3(NTOK, 2), b256, 0, stream>>>(presum, pos[0], pos[1], ln_w, ln_b, qc_bf, tgt2T);

    // 8. fused offsets+aw logits (N=384) -> oawb
    gemm_bf16<false, false, false, false, 64><<<dim3(3, 19, 2), b256, 0, stream>>>(
        qc_bf, nullptr, (size_t)STOK, 256, oaw_bf, 98304, 256, baw, 384,
        nullptr, nullptr, 0, oawb, (size_t)NTOK * 384, 384, NTOK, 256);

    // 9. sampling (fused softmax) -> samp bf16
    sample_kernel<<<dim3(600, 2), b256, 0, stream>>>(valb, oawb, ref[0], ref[1], samp);

    // 10. cout -> out2/out3 (t2_RGB / t2_T)
    gemm_bf16<false, false, false, false, 64><<<dim3(2, 19, 2), b256, 0, stream>>>(
        samp, nullptr, (size_t)STOK, 256, cout_bf, 65536, 256, cout_b, 256,
        nullptr, nullptr, 0, out2, (size_t)STOK, 256, NTOK, 256);

    // 11. norm1 (cross residuals fused)
    ln1_fused<<<dim3(NTOK, 2), b256, 0, stream>>>(tgt2T, out2, out3, ln_w, ln_b, ln1b, ln1f);

    // 12. FFN1 (ReLU, bf16 out)
    gemm_bf16<false, false, true, true, 64><<<dim3(8, 19, 2), b256, 0, stream>>>(
        ln1b, nullptr, (size_t)STOK, 256, ffn1_bf, 262144, 256, ffn_b1, 1024,
        nullptr, nullptr, 0, ffnh, (size_t)NTOK * 1024, 1024, NTOK, 256);

    // 13. FFN2 + residual(ln1f) -> ffny fp32
    gemm_bf16<false, true, false, false, 64><<<dim3(2, 19, 2), b256, 0, stream>>>(
        ffnh, nullptr, (size_t)NTOK * 1024, 1024, ffn2_bf, 262144, 1024, ffn_b2, 256,
        ln1f, ln1f + STOK, 256, ffny, (size_t)STOK, 256, NTOK, 1024);

    // 14. norm3 -> out0/out1
    ln3_kernel<<<dim3(NTOK, 2), b256, 0, stream>>>(ffny, ln_w, ln_b, out0, out1);
}

// Round 6
// 208.387 us; speedup vs baseline: 4.7402x; 1.0253x over previous
//
#include <hip/hip_runtime.h>
#include <cstddef>
#include <math.h>

#define NTOK 1200          // B*NQ = 4*300
#define LTOT_C 17821
#define MVAL 71284         // B*LTOT
#define STOK (NTOK * 256)  // 307200

typedef __attribute__((ext_vector_type(8))) short bhalf8;
typedef __attribute__((ext_vector_type(4))) float f32x4;

static __device__ __forceinline__ short f2bf(float f) {
    unsigned u = __builtin_bit_cast(unsigned, f);
    u += 0x7fffu + ((u >> 16) & 1u);   // RNE
    return (short)(u >> 16);
}
static __device__ __forceinline__ float bf2f(short s) {
    unsigned u = ((unsigned)(unsigned short)s) << 16;
    return __builtin_bit_cast(float, u);
}
static __device__ __forceinline__ bhalf8 cvt8(float4 a, float4 b) {
    bhalf8 h;
    h[0] = f2bf(a.x); h[1] = f2bf(a.y); h[2] = f2bf(a.z); h[3] = f2bf(a.w);
    h[4] = f2bf(b.x); h[5] = f2bf(b.y); h[6] = f2bf(b.z); h[7] = f2bf(b.w);
    return h;
}

// ---------------- weight convert fp32 -> bf16 (10 tasks) ----------------
struct WcvtArgs { const float* s[10]; short* d[10]; int n[10]; };
__global__ __launch_bounds__(256) void wcvt(WcvtArgs a) {
    const int ti = blockIdx.y;
    const float* s = a.s[ti];
    short* d = a.d[ti];
    const int n = a.n[ti];
    for (int base = (blockIdx.x * 256 + threadIdx.x) * 8; base < n; base += gridDim.x * 256 * 8) {
        const float4 f0 = *reinterpret_cast<const float4*>(s + base);
        const float4 f1 = *reinterpret_cast<const float4*>(s + base + 4);
        *reinterpret_cast<bhalf8*>(d + base) = cvt8(f0, f1);
    }
}

// ---------------- activation prep: qb=bf16(tgt+pos), tgtb=bf16(tgt), bias concat ----------------
__global__ __launch_bounds__(256) void prep_act(
    const float* __restrict__ tgt0, const float* __restrict__ tgt1,
    const float* __restrict__ pos0, const float* __restrict__ pos1,
    short* __restrict__ qb_bf, short* __restrict__ tgtb,
    const float* __restrict__ off_b, const float* __restrict__ aw_b,
    float* __restrict__ baw)
{
    const int z = blockIdx.y;
    if (blockIdx.x == 0 && z == 0) {
        for (int i = threadIdx.x; i < 768; i += 256) {
            const int zz = i / 384, j = i - zz * 384;
            baw[i] = (j < 256) ? off_b[zz * 256 + j] : aw_b[zz * 128 + (j - 256)];
        }
    }
    const float* tg = z ? tgt1 : tgt0;
    const float* ps = z ? pos1 : pos0;
    const int base = (blockIdx.x * 256 + threadIdx.x) * 8;
    if (base >= STOK) return;
    const float4 t0 = *reinterpret_cast<const float4*>(tg + base);
    const float4 t1 = *reinterpret_cast<const float4*>(tg + base + 4);
    const float4 p0 = *reinterpret_cast<const float4*>(ps + base);
    const float4 p1 = *reinterpret_cast<const float4*>(ps + base + 4);
    float4 s0 = make_float4(t0.x + p0.x, t0.y + p0.y, t0.z + p0.z, t0.w + p0.w);
    float4 s1 = make_float4(t1.x + p1.x, t1.y + p1.y, t1.z + p1.z, t1.w + p1.w);
    *reinterpret_cast<bhalf8*>(qb_bf + (size_t)z * STOK + base) = cvt8(s0, s1);
    *reinterpret_cast<bhalf8*>(tgtb + (size_t)z * STOK + base) = cvt8(t0, t1);
}

// ---------------- unified bf16 MFMA GEMM, 2-deep pipelined, static K-loop ----------------
// C = act( A[M,K=NK*64] @ W[N,K]^T + bias (+Res) ); tile BM x 128, 4 waves (2x2), BK=64.
// Depth-2 register prefetch with sched_barrier pinning so loads stay issued early.
template<bool A_FP32, bool HASRES, bool RELU, bool OUT_BF16, int BM, int NK>
__global__ __launch_bounds__(256) void gemm_bf16(
    const void* __restrict__ Av, const void* __restrict__ Av1, size_t aStrideZ, int lda,
    const short* __restrict__ Wv, size_t wStrideZ, int ldw,
    const float* __restrict__ bias, size_t biasStrideZ,
    const float* __restrict__ Res0, const float* __restrict__ Res1, int ldr,
    void* __restrict__ Cv, size_t cStrideZ, int ldc,
    int M)
{
    constexpr int AIT = BM / 32;   // A staging iterations (256 thr x 8 elems each)
    constexpr int MFR = BM / 32;   // m-fragments per wave (wave covers BM/2 rows)
    __shared__ short As[BM * 64];
    __shared__ short Bs[128 * 64];
    const int z = blockIdx.z;
    const void* Asel = (Av1 != nullptr && z == 1) ? Av1 : Av;
    const size_t zoff = (Av1 != nullptr) ? 0 : (size_t)z * aStrideZ;
    const short* W = Wv + (size_t)z * wStrideZ;
    const float* bz = bias + (size_t)z * biasStrideZ;
    const int t = threadIdx.x;
    const int wave = t >> 6, lane = t & 63;
    const int l15 = lane & 15, l4 = lane >> 4;
    const int wr = wave >> 1, wc = wave & 1;
    const int bm = blockIdx.y * BM, bn = blockIdx.x * 128;
    f32x4 acc[MFR][4] = {};

    float4 paf[2][AIT][2];   // A prefetch (fp32 path), two pipeline slots
    bhalf8 pab[2][AIT];      // A prefetch (bf16 path)
    bhalf8 pwb[2][4];        // W prefetch

    auto issue = [&](int slot, int k0) {
        #pragma unroll
        for (int i = 0; i < AIT; ++i) {
            const int G = t + i * 256;
            const int m = G >> 3, g = G & 7;
            const int row = bm + m;
            if (A_FP32) {
                if (row < M) {
                    const float* s = (const float*)Asel + zoff + (size_t)row * lda + k0 + g * 8;
                    paf[slot][i][0] = *reinterpret_cast<const float4*>(s);
                    paf[slot][i][1] = *reinterpret_cast<const float4*>(s + 4);
                } else {
                    paf[slot][i][0] = make_float4(0.f, 0.f, 0.f, 0.f);
                    paf[slot][i][1] = make_float4(0.f, 0.f, 0.f, 0.f);
                }
            } else {
                if (row < M) {
                    pab[slot][i] = *reinterpret_cast<const bhalf8*>(
                        (const short*)Asel + zoff + (size_t)row * lda + k0 + g * 8);
                } else {
                    #pragma unroll
                    for (int q = 0; q < 8; ++q) pab[slot][i][q] = 0;
                }
            }
        }
        #pragma unroll
        for (int i = 0; i < 4; ++i) {
            const int G = t + i * 256;
            const int n = G >> 3, g = G & 7;
            pwb[slot][i] = *reinterpret_cast<const bhalf8*>(W + (size_t)(bn + n) * ldw + k0 + g * 8);
        }
    };
    auto commit = [&](int slot) {
        #pragma unroll
        for (int i = 0; i < AIT; ++i) {
            const int G = t + i * 256;
            const int m = G >> 3, g = G & 7;
            bhalf8 h;
            if (A_FP32) h = cvt8(paf[slot][i][0], paf[slot][i][1]);
            else h = pab[slot][i];
            *reinterpret_cast<bhalf8*>(&As[m * 64 + ((g ^ (m & 7)) << 3)]) = h;
        }
        #pragma unroll
        for (int i = 0; i < 4; ++i) {
            const int G = t + i * 256;
            const int n = G >> 3, g = G & 7;
            *reinterpret_cast<bhalf8*>(&Bs[n * 64 + ((g ^ (n & 7)) << 3)]) = pwb[slot][i];
        }
    };
    auto compute = [&]() {
        #pragma unroll
        for (int kf = 0; kf < 2; ++kf) {
            bhalf8 af[MFR], bfv[4];
            #pragma unroll
            for (int mf = 0; mf < MFR; ++mf) {
                const int m = wr * (BM / 2) + (mf << 4) + l15;
                const int g = ((kf << 2) + l4) ^ (m & 7);
                af[mf] = *reinterpret_cast<const bhalf8*>(&As[m * 64 + (g << 3)]);
            }
            #pragma unroll
            for (int nf = 0; nf < 4; ++nf) {
                const int n = (wc << 6) + (nf << 4) + l15;
                const int g = ((kf << 2) + l4) ^ (n & 7);
                bfv[nf] = *reinterpret_cast<const bhalf8*>(&Bs[n * 64 + (g << 3)]);
            }
            #pragma unroll
            for (int mf = 0; mf < MFR; ++mf)
                #pragma unroll
                for (int nf = 0; nf < 4; ++nf)
                    acc[mf][nf] = __builtin_amdgcn_mfma_f32_16x16x32_bf16(
                        af[mf], bfv[nf], acc[mf][nf], 0, 0, 0);
        }
    };

    issue(0, 0);
    issue(1, 64);
    __builtin_amdgcn_sched_barrier(0);
    commit(0);
    #pragma unroll
    for (int ks = 0; ks < NK; ++ks) {
        __syncthreads();
        if (ks + 2 < NK) issue(ks & 1, (ks + 2) << 6);
        __builtin_amdgcn_sched_barrier(0);
        compute();
        __syncthreads();
        if (ks + 1 < NK) commit((ks + 1) & 1);
    }

    const float* Rz = HASRES ? (z ? Res1 : Res0) : nullptr;
    float br[4];
    #pragma unroll
    for (int nf = 0; nf < 4; ++nf) br[nf] = bz[bn + (wc << 6) + (nf << 4) + l15];
    #pragma unroll
    for (int mf = 0; mf < MFR; ++mf) {
        #pragma unroll
        for (int j = 0; j < 4; ++j) {
            const int row = bm + wr * (BM / 2) + (mf << 4) + (l4 << 2) + j;
            if (row >= M) continue;
            const int colbase = bn + (wc << 6);
            #pragma unroll
            for (int nf = 0; nf < 4; ++nf) {
                const int col = colbase + (nf << 4) + l15;
                float v = acc[mf][nf][j] + br[nf];
                if (HASRES) v += Rz[(size_t)row * ldr + col];
                if (RELU) v = fmaxf(v, 0.f);
                if (OUT_BF16)
                    ((short*)Cv + (size_t)z * cStrideZ)[(size_t)row * ldc + col] = f2bf(v);
                else
                    ((float*)Cv + (size_t)z * cStrideZ)[(size_t)row * ldc + col] = v;
            }
        }
    }
}

// ---------------- self-attention: key-parallel online softmax, bf16 out ----------------
__global__ __launch_bounds__(256) void attn2_kernel(
    const float* __restrict__ qkv_base, short* __restrict__ out_base)
{
    const float scale = 0.17677669529663687f;  // 1/sqrt(32)
    const float* qkv = qkv_base + (size_t)blockIdx.z * 921600;
    short* outp = out_base + (size_t)blockIdx.z * STOK;
    const int b = blockIdx.y >> 3, h = blockIdx.y & 7;
    const int t = threadIdx.x;
    const int ql = t & 31;
    const int kg = t >> 5;
    const int q = blockIdx.x * 32 + ql;
    const bool act = q < 300;
    const float* base = qkv + (size_t)b * 300 * 768;

    float qreg[32];
    if (act) {
        const float4* qp = reinterpret_cast<const float4*>(base + (size_t)q * 768 + h * 32);
        #pragma unroll
        for (int d4 = 0; d4 < 8; ++d4) {
            const float4 v = qp[d4];
            qreg[d4 * 4 + 0] = v.x; qreg[d4 * 4 + 1] = v.y;
            qreg[d4 * 4 + 2] = v.z; qreg[d4 * 4 + 3] = v.w;
        }
    }
    __shared__ float Ks[64][32];
    __shared__ float Vs[64][32];
    float m = -1e30f, l = 0.f, o[32];
    #pragma unroll
    for (int d = 0; d < 32; ++d) o[d] = 0.f;

    for (int k0 = 0; k0 < 300; k0 += 64) {
        const int cnt = min(64, 300 - k0);
        __syncthreads();
        for (int i = t; i < cnt * 32; i += 256) {
            const int kr = i >> 5, d = i & 31;
            Ks[kr][d] = base[(size_t)(k0 + kr) * 768 + 256 + h * 32 + d];
            Vs[kr][d] = base[(size_t)(k0 + kr) * 768 + 512 + h * 32 + d];
        }
        __syncthreads();
        if (act) {
            for (int kk = kg; kk < cnt; kk += 8) {
                const float4* krow = reinterpret_cast<const float4*>(&Ks[kk][0]);
                float s = 0.f;
                #pragma unroll
                for (int d4 = 0; d4 < 8; ++d4) {
                    const float4 kv = krow[d4];
                    s += qreg[d4 * 4 + 0] * kv.x + qreg[d4 * 4 + 1] * kv.y
                       + qreg[d4 * 4 + 2] * kv.z + qreg[d4 * 4 + 3] * kv.w;
                }
                s *= scale;
                const float4* vrow = reinterpret_cast<const float4*>(&Vs[kk][0]);
                if (s <= m) {
                    const float e = __expf(s - m);
                    l += e;
                    #pragma unroll
                    for (int d4 = 0; d4 < 8; ++d4) {
                        const float4 vv = vrow[d4];
                        o[d4 * 4 + 0] += e * vv.x; o[d4 * 4 + 1] += e * vv.y;
                        o[d4 * 4 + 2] += e * vv.z; o[d4 * 4 + 3] += e * vv.w;
                    }
                } else {
                    const float c = __expf(m - s);
                    l = l * c + 1.f;
                    #pragma unroll
                    for (int d4 = 0; d4 < 8; ++d4) {
                        const float4 vv = vrow[d4];
                        o[d4 * 4 + 0] = o[d4 * 4 + 0] * c + vv.x;
                        o[d4 * 4 + 1] = o[d4 * 4 + 1] * c + vv.y;
                        o[d4 * 4 + 2] = o[d4 * 4 + 2] * c + vv.z;
                        o[d4 * 4 + 3] = o[d4 * 4 + 3] * c + vv.w;
                    }
                    m = s;
                }
            }
        }
    }
    __shared__ float pm[32][8];
    __shared__ float pl[32][8];
    __shared__ float po[8][32][33];
    pm[ql][kg] = m; pl[ql][kg] = l;
    #pragma unroll
    for (int d = 0; d < 32; ++d) po[kg][d][ql] = o[d];
    __syncthreads();
    if (kg == 0) {
        float M = pm[ql][0];
        #pragma unroll
        for (int i = 1; i < 8; ++i) M = fmaxf(M, pm[ql][i]);
        float L = 0.f;
        #pragma unroll
        for (int i = 0; i < 8; ++i) L += pl[ql][i] * __expf(pm[ql][i] - M);
        const float invL = 1.f / L;
        #pragma unroll
        for (int i = 0; i < 8; ++i) pm[ql][i] = __expf(pm[ql][i] - M) * invL;
    }
    __syncthreads();
    if (act) {
        #pragma unroll
        for (int dd = 0; dd < 4; ++dd) {
            const int d = kg * 4 + dd;
            float v = 0.f;
            #pragma unroll
            for (int i = 0; i < 8; ++i) v += pm[ql][i] * po[i][d][ql];
            outp[((size_t)b * 300 + q) * 256 + h * 32 + d] = f2bf(v);
        }
    }
}

// ---------------- LN block-reduce body ----------------
#define LN_BODY(vexpr, widx)                                                  \
    const int row = blockIdx.x, t = threadIdx.x, z = blockIdx.y;              \
    (void)z;                                                                  \
    const int i = row * 256 + t;                                              \
    const float v = (vexpr);                                                  \
    __shared__ float r1[4], r2[4];                                            \
    float s = v;                                                              \
    _Pragma("unroll")                                                         \
    for (int o = 32; o; o >>= 1) s += __shfl_xor(s, o);                       \
    if ((t & 63) == 0) r1[t >> 6] = s;                                        \
    __syncthreads();                                                          \
    const float mean = (r1[0] + r1[1] + r1[2] + r1[3]) * (1.f / 256.f);       \
    const float dd = v - mean;                                                \
    float sq = dd * dd;                                                       \
    _Pragma("unroll")                                                         \
    for (int o = 32; o; o >>= 1) sq += __shfl_xor(sq, o);                     \
    if ((t & 63) == 0) r2[t >> 6] = sq;                                       \
    __syncthreads();                                                          \
    const float var = (r2[0] + r2[1] + r2[2] + r2[3]) * (1.f / 256.f);        \
    const float y = dd * rsqrtf(var + 1e-5f) * ln_w[(widx) * 256 + t]         \
                    + ln_b[(widx) * 256 + t];

// norm2 + qc=bf16(y+pos) + tgt2T (z=1 only)
__global__ __launch_bounds__(256) void ln2_fused(
    const float* __restrict__ presum, const float* __restrict__ pos0,
    const float* __restrict__ pos1, const float* __restrict__ ln_w,
    const float* __restrict__ ln_b, short* __restrict__ qc_bf,
    float* __restrict__ tgt2T)
{
    LN_BODY(presum[(size_t)z * STOK + i], z * 3 + 1)
    const float* pos = z ? pos1 : pos0;
    qc_bf[(size_t)z * STOK + i] = f2bf(y + pos[i]);
    if (z == 1) tgt2T[i] = y;
}

// norm1: z=0: LN(tgt2T+out2); z=1: LN(tgt2T+out2+out3); writes bf16 + fp32
__global__ __launch_bounds__(256) void ln1_fused(
    const float* __restrict__ tgt2T, const float* __restrict__ out2,
    const float* __restrict__ out3, const float* __restrict__ ln_w,
    const float* __restrict__ ln_b, short* __restrict__ ln1b,
    float* __restrict__ ln1f)
{
    LN_BODY(tgt2T[row * 256 + t] + out2[row * 256 + t] + (z ? out3[row * 256 + t] : 0.f), z * 3 + 0)
    ln1b[(size_t)z * STOK + i] = f2bf(y);
    ln1f[(size_t)z * STOK + i] = y;
}

// norm3: final outputs
__global__ __launch_bounds__(256) void ln3_kernel(
    const float* __restrict__ ffny, const float* __restrict__ ln_w,
    const float* __restrict__ ln_b, float* __restrict__ o0,
    float* __restrict__ o1)
{
    LN_BODY(ffny[(size_t)z * STOK + i], z * 3 + 2)
    (z ? o1 : o0)[i] = y;
}

// ---------------- deformable sampling v2: short4 gathers, wave=(q, head-half) ----------------
__global__ __launch_bounds__(256) void sample_kernel(
    const short* __restrict__ valb, const float* __restrict__ oaw,
    const float* __restrict__ ref0, const float* __restrict__ ref1,
    short* __restrict__ out)
{
    const int HL[4] = {100, 50, 25, 13};
    const int WL[4] = {134, 67, 34, 17};
    const int ST[4] = {0, 13400, 16750, 17600};
    const int z = blockIdx.y;
    const int t = threadIdx.x;
    const int wave = t >> 6, lane = t & 63;
    const int qi = wave >> 1, hh = wave & 1;
    const int pp = lane >> 5, h4 = (lane >> 3) & 3, dl = lane & 7;
    const int h = hh * 4 + h4;
    const int bq = blockIdx.x * 2 + qi;
    const int b = bq / 300;
    const float* op = oaw + ((size_t)z * NTOK + bq) * 384;
    const float* offp = op + h * 32;
    const float* awp  = op + 256 + h * 16;
    const float* refp = (z ? ref1 : ref0) + (size_t)bq * 8;
    const short* vb = valb + (size_t)z * MVAL * 256 + (size_t)b * LTOT_C * 256;
    const int co = h * 32 + dl * 4;

    float w16[16];
    float mx = -1e30f;
    #pragma unroll
    for (int i = 0; i < 16; ++i) { w16[i] = awp[i]; mx = fmaxf(mx, w16[i]); }
    float ssum = 0.f;
    #pragma unroll
    for (int i = 0; i < 16; ++i) { w16[i] = __expf(w16[i] - mx); ssum += w16[i]; }
    const float sinv = 1.f / ssum;

    float a0 = 0.f, a1 = 0.f, a2 = 0.f, a3 = 0.f;
#define TAP(cond, ridx, wv)                                                   \
    if (cond) {                                                               \
        const short4 sv = *reinterpret_cast<const short4*>(                   \
            vb + (size_t)(ridx) * 256 + co);                                  \
        a0 += (wv) * bf2f(sv.x); a1 += (wv) * bf2f(sv.y);                     \
        a2 += (wv) * bf2f(sv.z); a3 += (wv) * bf2f(sv.w);                     \
    }
    #pragma unroll
    for (int l = 0; l < 4; ++l) {
        const int Wl = WL[l], Hl = HL[l];
        const float rx = refp[l * 2] * (float)Wl - 0.5f;
        const float ry = refp[l * 2 + 1] * (float)Hl - 0.5f;
        #pragma unroll
        for (int j = 0; j < 2; ++j) {
            const int p = pp * 2 + j;
            const float px = rx + offp[(l * 4 + p) * 2];
            const float py = ry + offp[(l * 4 + p) * 2 + 1];
            const float wgt = w16[l * 4 + p] * sinv;
            const float x0f = floorf(px), y0f = floorf(py);
            const float wx = px - x0f, wy = py - y0f;
            const int x0 = (int)x0f, y0 = (int)y0f;
            const bool xa = (x0 >= 0) & (x0 < Wl);
            const bool xb = (x0 >= -1) & (x0 < Wl - 1);
            const bool ya = (y0 >= 0) & (y0 < Hl);
            const bool yb = (y0 >= -1) & (y0 < Hl - 1);
            const int rbase = ST[l] + y0 * Wl + x0;
            const float w00 = wgt * (1.f - wx) * (1.f - wy);
            const float w10 = wgt * wx * (1.f - wy);
            const float w01 = wgt * (1.f - wx) * wy;
            const float w11 = wgt * wx * wy;
            TAP(ya & xa, rbase, w00)
            TAP(ya & xb, rbase + 1, w10)
            TAP(yb & xa, rbase + Wl, w01)
            TAP(yb & xb, rbase + Wl + 1, w11)
        }
    }
#undef TAP
    a0 += __shfl_xor(a0, 32);
    a1 += __shfl_xor(a1, 32);
    a2 += __shfl_xor(a2, 32);
    a3 += __shfl_xor(a3, 32);
    if (pp == 0) {
        short4 o;
        o.x = f2bf(a0); o.y = f2bf(a1); o.z = f2bf(a2); o.w = f2bf(a3);
        *reinterpret_cast<short4*>(&out[((size_t)z * NTOK + bq) * 256 + co]) = o;
    }
}

extern "C" void kernel_launch(void* const* d_in, const int* in_sizes, int n_in,
                              void* d_out, int out_size, void* d_ws, size_t ws_size,
                              hipStream_t stream) {
    const float* tgt[2] = {(const float*)d_in[0], (const float*)d_in[1]};
    const float* pos[2] = {(const float*)d_in[2], (const float*)d_in[3]};
    const float* ref[2] = {(const float*)d_in[4], (const float*)d_in[5]};
    const float* src[2] = {(const float*)d_in[6], (const float*)d_in[7]};
    const float* sa_in_w  = (const float*)d_in[8];
    const float* sa_in_b  = (const float*)d_in[9];
    const float* sa_out_w = (const float*)d_in[10];
    const float* sa_out_b = (const float*)d_in[11];
    const float* ln_w = (const float*)d_in[12];
    const float* ln_b = (const float*)d_in[13];
    const float* ffn_w1 = (const float*)d_in[14];
    const float* ffn_b1 = (const float*)d_in[15];
    const float* ffn_w2 = (const float*)d_in[16];
    const float* ffn_b2 = (const float*)d_in[17];
    const float* val_w = (const float*)d_in[18];
    const float* val_b = (const float*)d_in[19];
    const float* off_w = (const float*)d_in[20];
    const float* off_b = (const float*)d_in[21];
    const float* aw_w = (const float*)d_in[22];
    const float* aw_b = (const float*)d_in[23];
    const float* cout_w = (const float*)d_in[24];
    const float* cout_b = (const float*)d_in[25];

    char* base = (char*)d_ws;
    size_t off = 0;
    auto alloc = [&](size_t bytes) -> char* {
        char* p = base + off;
        off += (bytes + 255) & ~(size_t)255;
        return p;
    };
    short* wbf   = (short*)alloc((size_t)2031616 * 2);
    float* baw   = (float*)alloc(768 * 4);
    short* qb_bf = (short*)alloc((size_t)2 * STOK * 2);
    short* tgtb  = (short*)alloc((size_t)2 * STOK * 2);
    float* qkv   = (float*)alloc((size_t)2 * 921600 * 4);
    short* attno = (short*)alloc((size_t)2 * STOK * 2);
    float* presum= (float*)alloc((size_t)2 * STOK * 4);
    short* qc_bf = (short*)alloc((size_t)2 * STOK * 2);
    float* tgt2T = (float*)alloc((size_t)STOK * 4);
    float* oawb  = (float*)alloc((size_t)2 * NTOK * 384 * 4);
    short* valb  = (short*)alloc((size_t)2 * MVAL * 256 * 2);
    short* samp  = (short*)alloc((size_t)2 * STOK * 2);
    short* ln1b  = (short*)alloc((size_t)2 * STOK * 2);
    float* ln1f  = (float*)alloc((size_t)2 * STOK * 4);
    short* ffnh  = (short*)alloc((size_t)2 * NTOK * 1024 * 2);
    float* ffny  = (float*)alloc((size_t)2 * STOK * 4);

    // weight sub-offsets (elements)
    short* sa_in_bf  = wbf + 0;        // 393216
    short* sa_out_bf = wbf + 393216;   // 131072
    short* ffn1_bf   = wbf + 524288;   // 524288
    short* ffn2_bf   = wbf + 1048576;  // 524288
    short* val_bf    = wbf + 1572864;  // 131072
    short* cout_bf   = wbf + 1703936;  // 131072
    short* oaw_bf    = wbf + 1835008;  // 196608 = 2 x (off 65536 + aw 32768)

    float* out0 = (float*)d_out;
    float* out1 = out0 + STOK;
    float* out2 = out1 + STOK;   // F_RGB = t2_RGB
    float* out3 = out2 + STOK;   // F_T

    const dim3 b256(256);

    // 1. weights -> bf16 (off/aw concatenated per z)
    WcvtArgs wa;
    wa.s[0] = sa_in_w;        wa.d[0] = sa_in_bf;       wa.n[0] = 393216;
    wa.s[1] = sa_out_w;       wa.d[1] = sa_out_bf;      wa.n[1] = 131072;
    wa.s[2] = ffn_w1;         wa.d[2] = ffn1_bf;        wa.n[2] = 524288;
    wa.s[3] = ffn_w2;         wa.d[3] = ffn2_bf;        wa.n[3] = 524288;
    wa.s[4] = val_w;          wa.d[4] = val_bf;         wa.n[4] = 131072;
    wa.s[5] = cout_w;         wa.d[5] = cout_bf;        wa.n[5] = 131072;
    wa.s[6] = off_w;          wa.d[6] = oaw_bf;         wa.n[6] = 65536;
    wa.s[7] = aw_w;           wa.d[7] = oaw_bf + 65536; wa.n[7] = 32768;
    wa.s[8] = off_w + 65536;  wa.d[8] = oaw_bf + 98304; wa.n[8] = 65536;
    wa.s[9] = aw_w + 32768;   wa.d[9] = oaw_bf + 163840;wa.n[9] = 32768;
    wcvt<<<dim3(128, 10), b256, 0, stream>>>(wa);

    // 2. activation prep + bias concat
    prep_act<<<dim3(150, 2), b256, 0, stream>>>(tgt[0], tgt[1], pos[0], pos[1],
                                                qb_bf, tgtb, off_b, aw_b, baw);

    // 3. value projections (z-batched, 2-deep pipelined): z=0 <- src_T, z=1 <- src_RGB
    gemm_bf16<true, false, false, true, 128, 4><<<dim3(2, 557, 2), b256, 0, stream>>>(
        src[1], src[0], 0, 256, val_bf, 65536, 256, val_b, 256, nullptr, nullptr, 0,
        valb, (size_t)MVAL * 256, 256, MVAL);

    // 4. in-proj qk (N=512) and v (N=256) -> qkv fp32 [z][1200][768]
    gemm_bf16<false, false, false, false, 64, 4><<<dim3(4, 19, 2), b256, 0, stream>>>(
        qb_bf, nullptr, (size_t)STOK, 256, sa_in_bf, 196608, 256, sa_in_b, 768,
        nullptr, nullptr, 0, qkv, 921600, 768, NTOK);
    gemm_bf16<false, false, false, false, 64, 4><<<dim3(2, 19, 2), b256, 0, stream>>>(
        tgtb, nullptr, (size_t)STOK, 256, sa_in_bf + 512 * 256, 196608, 256, sa_in_b + 512, 768,
        nullptr, nullptr, 0, qkv + 512, 921600, 768, NTOK);

    // 5. attention -> attno bf16
    attn2_kernel<<<dim3(10, 32, 2), b256, 0, stream>>>(qkv, attno);

    // 6. out-proj + residual(tgt) -> presum fp32
    gemm_bf16<false, true, false, false, 64, 4><<<dim3(2, 19, 2), b256, 0, stream>>>(
        attno, nullptr, (size_t)STOK, 256, sa_out_bf, 65536, 256, sa_out_b, 256,
        tgt[0], tgt[1], 256, presum, (size_t)STOK, 256, NTOK);

    // 7. norm2 + qc=bf16(LN+pos) + tgt2T
    ln2_fused<<<dim3(NTOK, 2), b256, 0, stream>>>(presum, pos[0], pos[1], ln_w, ln_b, qc_bf, tgt2T);

    // 8. fused offsets+aw logits (N=384) -> oawb
    gemm_bf16<false, false, false, false, 64, 4><<<dim3(3, 19, 2), b256, 0, stream>>>(
        qc_bf, nullptr, (size_t)STOK, 256, oaw_bf, 98304, 256, baw, 384,
        nullptr, nullptr, 0, oawb, (size_t)NTOK * 384, 384, NTOK);

    // 9. sampling (fused softmax) -> samp bf16
    sample_kernel<<<dim3(600, 2), b256, 0, stream>>>(valb, oawb, ref[0], ref[1], samp);

    // 10. cout -> out2/out3 (t2_RGB / t2_T)
    gemm_bf16<false, false, false, false, 64, 4><<<dim3(2, 19, 2), b256, 0, stream>>>(
        samp, nullptr, (size_t)STOK, 256, cout_bf, 65536, 256, cout_b, 256,
        nullptr, nullptr, 0, out2, (size_t)STOK, 256, NTOK);

    // 11. norm1 (cross residuals fused)
    ln1_fused<<<dim3(NTOK, 2), b256, 0, stream>>>(tgt2T, out2, out3, ln_w, ln_b, ln1b, ln1f);

    // 12. FFN1 (ReLU, bf16 out)
    gemm_bf16<false, false, true, true, 64, 4><<<dim3(8, 19, 2), b256, 0, stream>>>(
        ln1b, nullptr, (size_t)STOK, 256, ffn1_bf, 262144, 256, ffn_b1, 1024,
        nullptr, nullptr, 0, ffnh, (size_t)NTOK * 1024, 1024, NTOK);

    // 13. FFN2 + residual(ln1f) -> ffny fp32
    gemm_bf16<false, true, false, false, 64, 16><<<dim3(2, 19, 2), b256, 0, stream>>>(
        ffnh, nullptr, (size_t)NTOK * 1024, 1024, ffn2_bf, 262144, 1024, ffn_b2, 256,
        ln1f, ln1f + STOK, 256, ffny, (size_t)STOK, 256, NTOK);

    // 14. norm3 -> out0/out1
    ln3_kernel<<<dim3(NTOK, 2), b256, 0, stream>>>(ffny, ln_w, ln_b, out0, out1);
}